// Round 14
// baseline (234.529 us; speedup 1.0000x reference)
//
#include <hip/hip_runtime.h>

typedef __attribute__((ext_vector_type(8))) short bf16x8;
typedef __attribute__((ext_vector_type(4))) float f32x4;
typedef unsigned int uint32;
typedef unsigned long long ull;

#define NR 16384   // B*S rows
#define VD 1024    // value dim
#define ED 256     // embed dim
#define KC 8192    // codebook size
#define NBUCK 16   // top2 buckets per row (4 quarters x 4)
#define DELTA 2.0f // rescore margin (>= 2*max bf16 d2 noise ~0.9)
#define VSHIFT 128.0f // positivity shift: d2_rel min ~ +78 >> -128

__device__ __forceinline__ uint32 f2u(float f){ return __float_as_uint(f); }
__device__ __forceinline__ float u2f(uint32 u){ return __uint_as_float(u); }

// pack two f32 -> two bf16 (RNE) into one uint (lo16 = first elem)
__device__ __forceinline__ uint32 pkbf(float lo, float hi){
  uint32 a = __float_as_uint(lo); a += 0x7fffu + ((a >> 16) & 1u);
  uint32 b = __float_as_uint(hi); b += 0x7fffu + ((b >> 16) & 1u);
  return (a >> 16) | (b & 0xffff0000u);
}

#define GLOAD_LDS16(g, l) __builtin_amdgcn_global_load_lds( \
    (const __attribute__((address_space(1))) void*)(g),     \
    (__attribute__((address_space(3))) void*)(l), 16, 0, 0)
#define GLOAD_LDS4(g, l) __builtin_amdgcn_global_load_lds(  \
    (const __attribute__((address_space(1))) void*)(g),     \
    (__attribute__((address_space(3))) void*)(l), 4, 0, 0)

// ---------------- W f32 -> (hi trunc-bf16, lo RNE-bf16 of residual) ----------
__global__ __launch_bounds__(256) void wconv_kernel(
    const float* __restrict__ W, ushort* __restrict__ Whi, ushort* __restrict__ Wlo)
{
  const int idx = (blockIdx.x * 256 + threadIdx.x) * 8;
  float4 a = *(const float4*)(W + idx);
  float4 b = *(const float4*)(W + idx + 4);
  uint32 h01 = (f2u(a.x) >> 16) | (f2u(a.y) & 0xffff0000u);
  uint32 h23 = (f2u(a.z) >> 16) | (f2u(a.w) & 0xffff0000u);
  uint32 h45 = (f2u(b.x) >> 16) | (f2u(b.y) & 0xffff0000u);
  uint32 h67 = (f2u(b.z) >> 16) | (f2u(b.w) & 0xffff0000u);
  float r0 = a.x - u2f(f2u(a.x) & 0xffff0000u);
  float r1 = a.y - u2f(f2u(a.y) & 0xffff0000u);
  float r2 = a.z - u2f(f2u(a.z) & 0xffff0000u);
  float r3 = a.w - u2f(f2u(a.w) & 0xffff0000u);
  float r4 = b.x - u2f(f2u(b.x) & 0xffff0000u);
  float r5 = b.y - u2f(f2u(b.y) & 0xffff0000u);
  float r6 = b.z - u2f(f2u(b.z) & 0xffff0000u);
  float r7 = b.w - u2f(f2u(b.w) & 0xffff0000u);
  *(uint4*)(Whi + idx) = make_uint4(h01, h23, h45, h67);
  *(uint4*)(Wlo + idx) = make_uint4(pkbf(r0,r1), pkbf(r2,r3), pkbf(r4,r5), pkbf(r6,r7));
}

// ---------------- projection via split-bf16 MFMA (3-term, ~f32 exact) --------
__global__ __launch_bounds__(512) void proj_mfma(
    const float* __restrict__ V, const ushort* __restrict__ WhiG,
    const ushort* __restrict__ WloG, const float* __restrict__ bias,
    float* __restrict__ C, ushort* __restrict__ Pbf)
{
  __shared__ __align__(16) char lds[128 * 132 * 4];  // 67584 B; dbuf in first 64K
  const int rowbase = blockIdx.x * 128;
  const int colbase = blockIdx.y * 128;
  const int t = threadIdx.x, l = t & 63, w = t >> 6;
  const int c0 = l & 15, g = l >> 4;
  const int rg = w >> 2, cg = w & 3;

  const int srow = t >> 2, sq = t & 3;
  const float* aSrc = V + (size_t)(rowbase + srow) * VD + sq * 8;
  const int wu0 = (sq - (srow >> 3)) & 3;
  const ushort* whSrc = WhiG + (size_t)(colbase + srow) * VD + wu0 * 8;
  const ushort* wlSrc = WloG + (size_t)(colbase + srow) * VD + wu0 * 8;
  const int awOff = srow * 64 + (((sq + (srow >> 3)) & 3) << 4);
  char* wdst = lds + 16384 + (size_t)w * 1024;

  float4 bv[2];
  bv[0] = *(const float4*)&bias[colbase + cg * 32 + g * 4];
  bv[1] = *(const float4*)&bias[colbase + cg * 32 + 16 + g * 4];

  int vOff[4], wOff[2];
  #pragma unroll
  for (int bi = 0; bi < 4; ++bi) {
    int r = rg * 64 + bi * 16 + c0;
    vOff[bi] = r * 64 + (((g + (r >> 3)) & 3) << 4);
  }
  #pragma unroll
  for (int aj = 0; aj < 2; ++aj) {
    int r = cg * 32 + aj * 16 + c0;
    wOff[aj] = r * 64 + (((g + (r >> 3)) & 3) << 4);
  }

  f32x4 acc[2][4];
  #pragma unroll
  for (int aj = 0; aj < 2; ++aj)
    #pragma unroll
    for (int bi = 0; bi < 4; ++bi) acc[aj][bi] = (f32x4){0.f,0.f,0.f,0.f};

  float4 fa0, fa1;
  #define LOAD_A(ch)  { fa0 = *(const float4*)(aSrc + (ch) * 32); \
                        fa1 = *(const float4*)(aSrc + (ch) * 32 + 4); }
  #define STAGE_W(ch, buf) { \
    GLOAD_LDS16(whSrc + (ch) * 32, wdst + (buf) * 32768);        \
    GLOAD_LDS16(wlSrc + (ch) * 32, wdst + (buf) * 32768 + 8192); }
  #define CONV_WRITE(buf) { \
    uint32 h01 = (f2u(fa0.x)>>16)|(f2u(fa0.y)&0xffff0000u); \
    uint32 h23 = (f2u(fa0.z)>>16)|(f2u(fa0.w)&0xffff0000u); \
    uint32 h45 = (f2u(fa1.x)>>16)|(f2u(fa1.y)&0xffff0000u); \
    uint32 h67 = (f2u(fa1.z)>>16)|(f2u(fa1.w)&0xffff0000u); \
    float r0 = fa0.x - u2f(f2u(fa0.x)&0xffff0000u); \
    float r1 = fa0.y - u2f(f2u(fa0.y)&0xffff0000u); \
    float r2 = fa0.z - u2f(f2u(fa0.z)&0xffff0000u); \
    float r3 = fa0.w - u2f(f2u(fa0.w)&0xffff0000u); \
    float r4 = fa1.x - u2f(f2u(fa1.x)&0xffff0000u); \
    float r5 = fa1.y - u2f(f2u(fa1.y)&0xffff0000u); \
    float r6 = fa1.z - u2f(f2u(fa1.z)&0xffff0000u); \
    float r7 = fa1.w - u2f(f2u(fa1.w)&0xffff0000u); \
    *(uint4*)(lds + (buf)*32768 + awOff) = make_uint4(h01,h23,h45,h67); \
    *(uint4*)(lds + (buf)*32768 + 8192 + awOff) = \
        make_uint4(pkbf(r0,r1), pkbf(r2,r3), pkbf(r4,r5), pkbf(r6,r7)); }
  #define COMPUTE(buf) { \
    const char* Bq = lds + (buf) * 32768; \
    bf16x8 vh[4], vl[4], wh[2], wl[2]; \
    _Pragma("unroll") \
    for (int bi = 0; bi < 4; ++bi) { \
      vh[bi] = *(const bf16x8*)(Bq + vOff[bi]); \
      vl[bi] = *(const bf16x8*)(Bq + 8192 + vOff[bi]); } \
    _Pragma("unroll") \
    for (int aj = 0; aj < 2; ++aj) { \
      wh[aj] = *(const bf16x8*)(Bq + 16384 + wOff[aj]); \
      wl[aj] = *(const bf16x8*)(Bq + 24576 + wOff[aj]); } \
    _Pragma("unroll") \
    for (int aj = 0; aj < 2; ++aj) \
      _Pragma("unroll") \
      for (int bi = 0; bi < 4; ++bi) { \
        acc[aj][bi] = __builtin_amdgcn_mfma_f32_16x16x32_bf16(wh[aj], vh[bi], acc[aj][bi], 0, 0, 0); \
        acc[aj][bi] = __builtin_amdgcn_mfma_f32_16x16x32_bf16(wh[aj], vl[bi], acc[aj][bi], 0, 0, 0); \
        acc[aj][bi] = __builtin_amdgcn_mfma_f32_16x16x32_bf16(wl[aj], vh[bi], acc[aj][bi], 0, 0, 0); } }

  LOAD_A(0); STAGE_W(0, 0);
  CONV_WRITE(0);
  __syncthreads();
  int buf = 0;
  for (int ch = 0; ch < 32; ++ch) {
    if (ch < 31) { LOAD_A(ch + 1); STAGE_W(ch + 1, buf ^ 1); }
    COMPUTE(buf);
    if (ch < 31) CONV_WRITE(buf ^ 1);
    __syncthreads();
    buf ^= 1;
  }
  #undef LOAD_A
  #undef STAGE_W
  #undef CONV_WRITE
  #undef COMPUTE

  float* Cs = (float*)lds;
  #pragma unroll
  for (int aj = 0; aj < 2; ++aj)
    #pragma unroll
    for (int bi = 0; bi < 4; ++bi) {
      int prow = rg * 64 + bi * 16 + c0;
      int pcol = cg * 32 + aj * 16 + g * 4;
      f32x4 v = acc[aj][bi];
      float4 o = make_float4(v[0] + bv[aj].x, v[1] + bv[aj].y,
                             v[2] + bv[aj].z, v[3] + bv[aj].w);
      *(float4*)&Cs[prow * 132 + pcol] = o;
    }
  __syncthreads();
  {
    const int row = t >> 2, qd = t & 3;
    const float* src = &Cs[row * 132 + qd * 32];
    float* cdst = &C[(size_t)(rowbase + row) * ED + colbase + qd * 32];
    float4 vv[8];
    #pragma unroll
    for (int i = 0; i < 8; ++i) vv[i] = *(const float4*)(src + i * 4);
    #pragma unroll
    for (int i = 0; i < 8; ++i) *(float4*)(cdst + i * 4) = vv[i];
    uint4 pk[4];
    #pragma unroll
    for (int i = 0; i < 4; ++i)
      pk[i] = make_uint4(pkbf(vv[2*i].x, vv[2*i].y), pkbf(vv[2*i].z, vv[2*i].w),
                         pkbf(vv[2*i+1].x, vv[2*i+1].y), pkbf(vv[2*i+1].z, vv[2*i+1].w));
    uint4* pdst = (uint4*)&Pbf[(size_t)(rowbase + row) * ED + colbase + qd * 32];
    #pragma unroll
    for (int i = 0; i < 4; ++i) pdst[i] = pk[i];
  }
}

// ---------------- codebook norms (f64) + bf16(-2c) emission ----------------
__global__ __launch_bounds__(256) void cnormbf_kernel(
    const float* __restrict__ CB, float* __restrict__ cnorm,
    float* __restrict__ cnAdj, ushort* __restrict__ CBbf)
{
  const int t = threadIdx.x, lane = t & 63, w = t >> 6;
  const int code = blockIdx.x * 4 + w;
  float4 c = *(const float4*)&CB[(size_t)code * ED + lane * 4];
  uint2 pk = make_uint2(pkbf(-2.f * c.x, -2.f * c.y), pkbf(-2.f * c.z, -2.f * c.w));
  *(uint2*)&CBbf[(size_t)code * ED + lane * 4] = pk;
  double s = (double)c.x * c.x + (double)c.y * c.y + (double)c.z * c.z + (double)c.w * c.w;
  #pragma unroll
  for (int off = 32; off; off >>= 1) s += __shfl_down(s, off, 64);
  if (lane == 0) {
    cnorm[code] = (float)s;
    cnAdj[code] = (float)s + VSHIFT;
  }
}

// ---------------- code-streaming MFMA distance, 4 blocks/CU ----------
// Grid: 1024 blocks = 256 row-blocks (64 rows) x 4 code-quarters. 512 thr =
// 8 waves (rg = w>>1 of 4: 16 rows each; cg = w&1: 16 codes of each 32-chunk).
// LDS 34.5 KB: 32 KB Tile (P-stage union 2x16KB code dbuf) -> 4 blocks/CU =
// 32 waves/CU. Fold/flush semantics byte-identical to the proven R13 u64 path.
__global__ __launch_bounds__(512, 4) void mfma_dist(
    const ushort* __restrict__ CBbf, const ushort* __restrict__ Pbf,
    const float* __restrict__ cnAdj, uint4* __restrict__ top2s)
{
  __shared__ uint4 Tile[2048];                 // 32 KB
  __shared__ __align__(16) float cnL[2][64];   // two 64-code cn pairs
  __shared__ ull msh[64][2][2];

  const int bx = blockIdx.x;
  const int h = bx & 3;                 // code quarter
  const int rowbase = (bx >> 2) * 64;
  const int cq0 = h * 2048;
  const int t = threadIdx.x, l = t & 63, w = t >> 6;
  const int rg = w >> 1, cg = w & 1;
  const int c0 = l & 15, g = l >> 4;

  // ---- P prologue: stage 64x256 bf16 (32 KB), swizzle (u + row) & 31 ----
  {
    const ushort* gb = Pbf + ((size_t)rowbase << 8);
    #pragma unroll
    for (int i = 0; i < 4; ++i) {
      int lin = i * 8192 + t * 16;
      int crow = lin >> 9;
      int u = (lin >> 4) & 31;
      GLOAD_LDS16(gb + ((size_t)crow << 8) + (((u - crow) & 31) << 3),
                  (char*)Tile + lin);
    }
  }
  __syncthreads();
  bf16x8 breg[8];
  {
    const char* Tb = (const char*)Tile;
    const int prow = rg * 16 + c0;
    #pragma unroll
    for (int kk = 0; kk < 8; ++kk)
      breg[kk] = *(const bf16x8*)(Tb + prow * 512 + (((kk * 4 + g + prow) & 31) << 4));
  }
  __syncthreads();

  const int cl0 = cg * 16 + c0;        // A row (code) for this lane
  const int ab0 = cl0 * 512;
  ull k1 = ~0ull, k2 = ~0ull;

  // rolling staging pointers: advance 32 codes (16 KB) per chunk
  const ushort* sp0; const ushort* sp1; int lo0, lo1;
  {
    int lin = t * 16;
    int crow = lin >> 9;
    int u = (lin >> 4) & 31;
    sp0 = CBbf + (((size_t)(cq0 + crow)) << 8) + (((u - crow) & 31) << 3);
    lo0 = lin;
    lin = 8192 + t * 16;
    crow = lin >> 9;
    u = (lin >> 4) & 31;
    sp1 = CBbf + (((size_t)(cq0 + crow)) << 8) + (((u - crow) & 31) << 3);
    lo1 = lin;
  }
  const float* cnp = cnAdj + cq0 + l;

  // stage chunk 0 into buf0 + cn pair 0 (covers chunks 0,1)
  {
    char* db = (char*)Tile;
    GLOAD_LDS16(sp0, db + lo0); sp0 += 8192;
    GLOAD_LDS16(sp1, db + lo1); sp1 += 8192;
    if (w == 0) GLOAD_LDS4(cnp, (char*)&cnL[0][0]);
    cnp += 64;
  }
  __syncthreads();

  // BODY(buf, ch, SCN): compute chunk ch from buffer buf; stage ch+1 into
  // buf^1; SCN=1 (odd ch) also stages the cn pair for chunks ch+1, ch+2.
  #define BODY(bufc, ch, SCN)                                              \
  {                                                                        \
    if ((ch) < 63) {                                                       \
      char* db = (char*)Tile + ((bufc) ^ 1) * 16384;                       \
      GLOAD_LDS16(sp0, db + lo0); sp0 += 8192;                             \
      GLOAD_LDS16(sp1, db + lo1); sp1 += 8192;                             \
      if (SCN) {                                                           \
        if (w == 0) GLOAD_LDS4(cnp, (char*)&cnL[(((ch) + 1) >> 1) & 1][0]);\
        cnp += 64;                                                         \
      }                                                                    \
    }                                                                      \
    f32x4 acc = *(const f32x4*)&cnL[((ch) >> 1) & 1][((ch) & 1) * 32 + cg * 16 + g * 4]; \
    {                                                                      \
      const char* Tb = (const char*)Tile + (bufc) * 16384;                 \
      int u0 = (g + cl0) & 31;                                             \
      _Pragma("unroll")                                                    \
      for (int kk = 0; kk < 8; ++kk) {                                     \
        bf16x8 a0 = *(const bf16x8*)(Tb + ab0 + (u0 << 4));                \
        u0 = (u0 + 4) & 31;                                                \
        acc = __builtin_amdgcn_mfma_f32_16x16x32_bf16(a0, breg[kk], acc, 0, 0, 0); \
      }                                                                    \
    }                                                                      \
    {                                                                      \
      const int cbase = cq0 + (ch) * 32 + cg * 16 + g * 4;                 \
      _Pragma("unroll")                                                    \
      for (int q = 0; q < 4; ++q) {                                        \
        ull key = ((ull)f2u(acc[q]) << 32) | (ull)(cbase + q);             \
        ull mx = k1 > key ? k1 : key;                                      \
        k1 = k1 < key ? k1 : key;                                          \
        k2 = k2 < mx ? k2 : mx;                                            \
      }                                                                    \
    }                                                                      \
    if (((ch) & 15) == 15) {                                               \
      ull K1 = k1, K2 = k2;                                                \
      _Pragma("unroll")                                                    \
      for (int mask = 16; mask <= 32; mask <<= 1) {                        \
        ull o1 = __shfl_xor(K1, mask);                                     \
        ull o2 = __shfl_xor(K2, mask);                                     \
        ull mxq = K1 > o1 ? K1 : o1;                                       \
        ull mn2 = K2 < o2 ? K2 : o2;                                       \
        K1 = K1 < o1 ? K1 : o1;                                            \
        K2 = mxq < mn2 ? mxq : mn2;                                        \
      }                                                                    \
      if (g == 0) {                                                        \
        msh[rg * 16 + c0][cg][0] = K1;                                     \
        msh[rg * 16 + c0][cg][1] = K2;                                     \
      }                                                                    \
      k1 = ~0ull; k2 = ~0ull;                                              \
      __syncthreads();                                                     \
      if (t < 64) {                                                        \
        ull a1 = msh[t][0][0], a2 = msh[t][0][1];                          \
        ull b1 = msh[t][1][0], b2 = msh[t][1][1];                          \
        ull K1f = a1 < b1 ? a1 : b1;                                       \
        ull mxf = a1 > b1 ? a1 : b1;                                       \
        ull mn2f = a2 < b2 ? a2 : b2;                                      \
        ull K2f = mxf < mn2f ? mxf : mn2f;                                 \
        top2s[(size_t)(h * 4 + ((ch) >> 4)) * NR + rowbase + t] =          \
            make_uint4((uint32)(K1f >> 32), (uint32)K1f,                   \
                       (uint32)(K2f >> 32), (uint32)K2f);                  \
      }                                                                    \
    }                                                                      \
    __syncthreads();                                                       \
  }

  for (int ch = 0; ch < 64; ch += 2) {
    BODY(0, ch, 0);
    BODY(1, ch + 1, 1);
  }
  #undef BODY
}

// ---------------- exact rescore: 1 wave per row, wave-parallel f64 dots -------
__global__ __launch_bounds__(256) void rescore_kernel(
    const uint4* __restrict__ top2s, const float* __restrict__ P,
    const float* __restrict__ CBF, const float* __restrict__ cnorm,
    int* __restrict__ ids, float* __restrict__ out_ids)
{
  const int t = threadIdx.x, l = t & 63, w = t >> 6;
  const int row = blockIdx.x * 4 + w;
  float m1 = 3.4e38f, m2 = 3.4e38f;     // shifted-domain values (v' = d2 + VSHIFT)
  uint32 i1 = 0, i2 = 0;
  if (l < NBUCK) {
    uint4 e = top2s[(size_t)l * NR + row];
    m1 = u2f(e.x); i1 = e.y & 8191u;
    m2 = u2f(e.z); i2 = e.w & 8191u;
  }
  float rm = m1;
  #pragma unroll
  for (int mask = 1; mask < 64; mask <<= 1) rm = fminf(rm, __shfl_xor(rm, mask));
  const float thr = rm + DELTA;         // shift cancels in the comparison
  ull qm1 = __ballot(l < NBUCK && m1 <= thr);
  ull qm2 = __ballot(l < NBUCK && m2 <= thr);
  float4 p = *(const float4*)&P[(size_t)row * ED + l * 4];
  double bd = 1e300; int bi = 0x7fffffff;
  #pragma unroll
  for (int cand = 0; cand < 2; ++cand) {
    ull qm = cand ? qm2 : qm1;
    uint32 myi = cand ? i2 : i1;
    while (qm) {
      int b = __ffsll(qm) - 1; qm &= qm - 1;
      int idx = __shfl((int)myi, b);
      const float4 c = *(const float4*)&CBF[(size_t)idx * ED + l * 4];
      double s = (double)p.x * c.x + (double)p.y * c.y + (double)p.z * c.z + (double)p.w * c.w;
      #pragma unroll
      for (int mask = 1; mask < 64; mask <<= 1) s += __shfl_xor(s, mask);
      double d2 = (double)cnorm[idx] - 2.0 * s;
      if (d2 < bd || (d2 == bd && idx < bi)) { bd = d2; bi = idx; }
    }
  }
  if (l == 0) {
    ids[row] = bi;
    out_ids[row] = (float)bi;
  }
}

// ---------------- gather quantized + vq_loss ----------------
__global__ __launch_bounds__(256) void gather_loss(
    const float* __restrict__ P, const float* __restrict__ CB,
    const int* __restrict__ ids, float* __restrict__ outq,
    float* __restrict__ loss)
{
  const int t = threadIdx.x, lane = t & 63, w = t >> 6;
  const int row = blockIdx.x * 4 + w;
  const int id = ids[row];
  float4 q = *(const float4*)&CB[(size_t)id * ED + lane * 4];
  float4 p = *(const float4*)&P[(size_t)row * ED + lane * 4];
  *(float4*)&outq[(size_t)row * ED + lane * 4] = q;
  float dx = p.x - q.x, dy = p.y - q.y, dz = p.z - q.z, dw = p.w - q.w;
  float s = dx * dx + dy * dy + dz * dz + dw * dw;
  #pragma unroll
  for (int off = 32; off; off >>= 1) s += __shfl_down(s, off, 64);
  __shared__ float partial[4];
  if (lane == 0) partial[w] = s;
  __syncthreads();
  if (t == 0){
    float tot = partial[0] + partial[1] + partial[2] + partial[3];
    atomicAdd(loss, tot * (1.25f / ((float)NR * (float)ED)));
  }
}

extern "C" void kernel_launch(void* const* d_in, const int* in_sizes, int n_in,
                              void* d_out, int out_size, void* d_ws, size_t ws_size,
                              hipStream_t stream) {
    const float* values = (const float*)d_in[0];   // [8,2048,1024]
    const float* W      = (const float*)d_in[1];   // [256,1024]
    const float* bias   = (const float*)d_in[2];   // [256]
    const float* CB     = (const float*)d_in[3];   // [8192,256]

    float* out      = (float*)d_out;
    float* out_q    = out;                                  // NR*ED (16 MB)
    float* out_ids  = out + (size_t)NR * ED;                // NR
    float* out_loss = out_ids + NR;                         // 1

    // out_q region doubles as scratch before gather_loss overwrites it:
    //   [0, 4MB)  : top2s (NBUCK x NR x 16 B = 4 MB)
    //   [4MB,12MB): Pbf   (NR x ED bf16 = 8 MB)
    uint4*  top2s = (uint4*)out_q;
    ushort* Pbf   = (ushort*)(out_q + (size_t)NBUCK * NR * 4);  // +4MB in floats

    float*  proj  = (float*)d_ws;                           // 16 MB
    float*  cnorm = proj + (size_t)NR * ED;                 // 32 KB
    float*  cnAdj = cnorm + KC;                             // 32 KB
    ushort* CBbf  = (ushort*)(cnAdj + KC);                  // 4 MB
    int*    ids   = (int*)(CBbf + (size_t)KC * ED);         // 64 KB
    ushort* Whi   = (ushort*)(ids + NR);                    // 512 KB
    ushort* Wlo   = Whi + (size_t)ED * VD;                  // 512 KB

    hipMemsetAsync(out_loss, 0, sizeof(float), stream);
    wconv_kernel<<<ED * VD / (256 * 8), 256, 0, stream>>>(W, Whi, Wlo);
    cnormbf_kernel<<<KC / 4, 256, 0, stream>>>(CB, cnorm, cnAdj, CBbf);
    proj_mfma<<<dim3(NR / 128, ED / 128), 512, 0, stream>>>(values, Whi, Wlo, bias, proj, Pbf);
    mfma_dist<<<1024, 512, 0, stream>>>(CBbf, Pbf, cnAdj, top2s);
    rescore_kernel<<<NR / 4, 256, 0, stream>>>(top2s, proj, CB, cnorm, ids, out_ids);
    gather_loss<<<NR / 4, 256, 0, stream>>>(proj, CB, ids, out_q, out_loss);
}

// Round 15
// 210.630 us; speedup vs baseline: 1.1135x; 1.1135x over previous
//
#include <hip/hip_runtime.h>

typedef __attribute__((ext_vector_type(8))) short bf16x8;
typedef __attribute__((ext_vector_type(4))) float f32x4;
typedef unsigned int uint32;
typedef unsigned long long ull;

#define NR 16384   // B*S rows
#define VD 1024    // value dim
#define ED 256     // embed dim
#define KC 8192    // codebook size
#define NBUCK 16   // top2 buckets per row (4 quarters x 4)
#define DELTA 2.0f // rescore margin (>= 2*max bf16 d2 noise ~0.9)
#define VSHIFT 128.0f // positivity shift: d2_rel min ~ +78 >> -128

__device__ __forceinline__ uint32 f2u(float f){ return __float_as_uint(f); }
__device__ __forceinline__ float u2f(uint32 u){ return __uint_as_float(u); }

// pack two f32 -> two bf16 (RNE) into one uint (lo16 = first elem)
__device__ __forceinline__ uint32 pkbf(float lo, float hi){
  uint32 a = __float_as_uint(lo); a += 0x7fffu + ((a >> 16) & 1u);
  uint32 b = __float_as_uint(hi); b += 0x7fffu + ((b >> 16) & 1u);
  return (a >> 16) | (b & 0xffff0000u);
}

#define GLOAD_LDS16(g, l) __builtin_amdgcn_global_load_lds( \
    (const __attribute__((address_space(1))) void*)(g),     \
    (__attribute__((address_space(3))) void*)(l), 16, 0, 0)
#define GLOAD_LDS4(g, l) __builtin_amdgcn_global_load_lds(  \
    (const __attribute__((address_space(1))) void*)(g),     \
    (__attribute__((address_space(3))) void*)(l), 4, 0, 0)

// ---------------- W f32 -> (hi trunc-bf16, lo RNE-bf16 of residual) ----------
__global__ __launch_bounds__(256) void wconv_kernel(
    const float* __restrict__ W, ushort* __restrict__ Whi, ushort* __restrict__ Wlo)
{
  const int idx = (blockIdx.x * 256 + threadIdx.x) * 8;
  float4 a = *(const float4*)(W + idx);
  float4 b = *(const float4*)(W + idx + 4);
  uint32 h01 = (f2u(a.x) >> 16) | (f2u(a.y) & 0xffff0000u);
  uint32 h23 = (f2u(a.z) >> 16) | (f2u(a.w) & 0xffff0000u);
  uint32 h45 = (f2u(b.x) >> 16) | (f2u(b.y) & 0xffff0000u);
  uint32 h67 = (f2u(b.z) >> 16) | (f2u(b.w) & 0xffff0000u);
  float r0 = a.x - u2f(f2u(a.x) & 0xffff0000u);
  float r1 = a.y - u2f(f2u(a.y) & 0xffff0000u);
  float r2 = a.z - u2f(f2u(a.z) & 0xffff0000u);
  float r3 = a.w - u2f(f2u(a.w) & 0xffff0000u);
  float r4 = b.x - u2f(f2u(b.x) & 0xffff0000u);
  float r5 = b.y - u2f(f2u(b.y) & 0xffff0000u);
  float r6 = b.z - u2f(f2u(b.z) & 0xffff0000u);
  float r7 = b.w - u2f(f2u(b.w) & 0xffff0000u);
  *(uint4*)(Whi + idx) = make_uint4(h01, h23, h45, h67);
  *(uint4*)(Wlo + idx) = make_uint4(pkbf(r0,r1), pkbf(r2,r3), pkbf(r4,r5), pkbf(r6,r7));
}

// ---------------- projection via split-bf16 MFMA (3-term, ~f32 exact) --------
__global__ __launch_bounds__(512) void proj_mfma(
    const float* __restrict__ V, const ushort* __restrict__ WhiG,
    const ushort* __restrict__ WloG, const float* __restrict__ bias,
    float* __restrict__ C, ushort* __restrict__ Pbf)
{
  __shared__ __align__(16) char lds[128 * 132 * 4];  // 67584 B; dbuf in first 64K
  const int rowbase = blockIdx.x * 128;
  const int colbase = blockIdx.y * 128;
  const int t = threadIdx.x, l = t & 63, w = t >> 6;
  const int c0 = l & 15, g = l >> 4;
  const int rg = w >> 2, cg = w & 3;

  const int srow = t >> 2, sq = t & 3;
  const float* aSrc = V + (size_t)(rowbase + srow) * VD + sq * 8;
  const int wu0 = (sq - (srow >> 3)) & 3;
  const ushort* whSrc = WhiG + (size_t)(colbase + srow) * VD + wu0 * 8;
  const ushort* wlSrc = WloG + (size_t)(colbase + srow) * VD + wu0 * 8;
  const int awOff = srow * 64 + (((sq + (srow >> 3)) & 3) << 4);
  char* wdst = lds + 16384 + (size_t)w * 1024;

  float4 bv[2];
  bv[0] = *(const float4*)&bias[colbase + cg * 32 + g * 4];
  bv[1] = *(const float4*)&bias[colbase + cg * 32 + 16 + g * 4];

  int vOff[4], wOff[2];
  #pragma unroll
  for (int bi = 0; bi < 4; ++bi) {
    int r = rg * 64 + bi * 16 + c0;
    vOff[bi] = r * 64 + (((g + (r >> 3)) & 3) << 4);
  }
  #pragma unroll
  for (int aj = 0; aj < 2; ++aj) {
    int r = cg * 32 + aj * 16 + c0;
    wOff[aj] = r * 64 + (((g + (r >> 3)) & 3) << 4);
  }

  f32x4 acc[2][4];
  #pragma unroll
  for (int aj = 0; aj < 2; ++aj)
    #pragma unroll
    for (int bi = 0; bi < 4; ++bi) acc[aj][bi] = (f32x4){0.f,0.f,0.f,0.f};

  float4 fa0, fa1;
  #define LOAD_A(ch)  { fa0 = *(const float4*)(aSrc + (ch) * 32); \
                        fa1 = *(const float4*)(aSrc + (ch) * 32 + 4); }
  #define STAGE_W(ch, buf) { \
    GLOAD_LDS16(whSrc + (ch) * 32, wdst + (buf) * 32768);        \
    GLOAD_LDS16(wlSrc + (ch) * 32, wdst + (buf) * 32768 + 8192); }
  #define CONV_WRITE(buf) { \
    uint32 h01 = (f2u(fa0.x)>>16)|(f2u(fa0.y)&0xffff0000u); \
    uint32 h23 = (f2u(fa0.z)>>16)|(f2u(fa0.w)&0xffff0000u); \
    uint32 h45 = (f2u(fa1.x)>>16)|(f2u(fa1.y)&0xffff0000u); \
    uint32 h67 = (f2u(fa1.z)>>16)|(f2u(fa1.w)&0xffff0000u); \
    float r0 = fa0.x - u2f(f2u(fa0.x)&0xffff0000u); \
    float r1 = fa0.y - u2f(f2u(fa0.y)&0xffff0000u); \
    float r2 = fa0.z - u2f(f2u(fa0.z)&0xffff0000u); \
    float r3 = fa0.w - u2f(f2u(fa0.w)&0xffff0000u); \
    float r4 = fa1.x - u2f(f2u(fa1.x)&0xffff0000u); \
    float r5 = fa1.y - u2f(f2u(fa1.y)&0xffff0000u); \
    float r6 = fa1.z - u2f(f2u(fa1.z)&0xffff0000u); \
    float r7 = fa1.w - u2f(f2u(fa1.w)&0xffff0000u); \
    *(uint4*)(lds + (buf)*32768 + awOff) = make_uint4(h01,h23,h45,h67); \
    *(uint4*)(lds + (buf)*32768 + 8192 + awOff) = \
        make_uint4(pkbf(r0,r1), pkbf(r2,r3), pkbf(r4,r5), pkbf(r6,r7)); }
  #define COMPUTE(buf) { \
    const char* Bq = lds + (buf) * 32768; \
    bf16x8 vh[4], vl[4], wh[2], wl[2]; \
    _Pragma("unroll") \
    for (int bi = 0; bi < 4; ++bi) { \
      vh[bi] = *(const bf16x8*)(Bq + vOff[bi]); \
      vl[bi] = *(const bf16x8*)(Bq + 8192 + vOff[bi]); } \
    _Pragma("unroll") \
    for (int aj = 0; aj < 2; ++aj) { \
      wh[aj] = *(const bf16x8*)(Bq + 16384 + wOff[aj]); \
      wl[aj] = *(const bf16x8*)(Bq + 24576 + wOff[aj]); } \
    _Pragma("unroll") \
    for (int aj = 0; aj < 2; ++aj) \
      _Pragma("unroll") \
      for (int bi = 0; bi < 4; ++bi) { \
        acc[aj][bi] = __builtin_amdgcn_mfma_f32_16x16x32_bf16(wh[aj], vh[bi], acc[aj][bi], 0, 0, 0); \
        acc[aj][bi] = __builtin_amdgcn_mfma_f32_16x16x32_bf16(wh[aj], vl[bi], acc[aj][bi], 0, 0, 0); \
        acc[aj][bi] = __builtin_amdgcn_mfma_f32_16x16x32_bf16(wl[aj], vh[bi], acc[aj][bi], 0, 0, 0); } }

  LOAD_A(0); STAGE_W(0, 0);
  CONV_WRITE(0);
  __syncthreads();
  int buf = 0;
  for (int ch = 0; ch < 32; ++ch) {
    if (ch < 31) { LOAD_A(ch + 1); STAGE_W(ch + 1, buf ^ 1); }
    COMPUTE(buf);
    if (ch < 31) CONV_WRITE(buf ^ 1);
    __syncthreads();
    buf ^= 1;
  }
  #undef LOAD_A
  #undef STAGE_W
  #undef CONV_WRITE
  #undef COMPUTE

  float* Cs = (float*)lds;
  #pragma unroll
  for (int aj = 0; aj < 2; ++aj)
    #pragma unroll
    for (int bi = 0; bi < 4; ++bi) {
      int prow = rg * 64 + bi * 16 + c0;
      int pcol = cg * 32 + aj * 16 + g * 4;
      f32x4 v = acc[aj][bi];
      float4 o = make_float4(v[0] + bv[aj].x, v[1] + bv[aj].y,
                             v[2] + bv[aj].z, v[3] + bv[aj].w);
      *(float4*)&Cs[prow * 132 + pcol] = o;
    }
  __syncthreads();
  {
    const int row = t >> 2, qd = t & 3;
    const float* src = &Cs[row * 132 + qd * 32];
    float* cdst = &C[(size_t)(rowbase + row) * ED + colbase + qd * 32];
    float4 vv[8];
    #pragma unroll
    for (int i = 0; i < 8; ++i) vv[i] = *(const float4*)(src + i * 4);
    #pragma unroll
    for (int i = 0; i < 8; ++i) *(float4*)(cdst + i * 4) = vv[i];
    uint4 pk[4];
    #pragma unroll
    for (int i = 0; i < 4; ++i)
      pk[i] = make_uint4(pkbf(vv[2*i].x, vv[2*i].y), pkbf(vv[2*i].z, vv[2*i].w),
                         pkbf(vv[2*i+1].x, vv[2*i+1].y), pkbf(vv[2*i+1].z, vv[2*i+1].w));
    uint4* pdst = (uint4*)&Pbf[(size_t)(rowbase + row) * ED + colbase + qd * 32];
    #pragma unroll
    for (int i = 0; i < 4; ++i) pdst[i] = pk[i];
  }
}

// ---------------- codebook norms (f64) + bf16(-2c) emission ----------------
__global__ __launch_bounds__(256) void cnormbf_kernel(
    const float* __restrict__ CB, float* __restrict__ cnorm,
    float* __restrict__ cnAdj, ushort* __restrict__ CBbf)
{
  const int t = threadIdx.x, lane = t & 63, w = t >> 6;
  const int code = blockIdx.x * 4 + w;
  float4 c = *(const float4*)&CB[(size_t)code * ED + lane * 4];
  uint2 pk = make_uint2(pkbf(-2.f * c.x, -2.f * c.y), pkbf(-2.f * c.z, -2.f * c.w));
  *(uint2*)&CBbf[(size_t)code * ED + lane * 4] = pk;
  double s = (double)c.x * c.x + (double)c.y * c.y + (double)c.z * c.z + (double)c.w * c.w;
  #pragma unroll
  for (int off = 32; off; off >>= 1) s += __shfl_down(s, off, 64);
  if (lane == 0) {
    cnorm[code] = (float)s;
    cnAdj[code] = (float)s + VSHIFT;
  }
}

// ---------------- code-streaming MFMA distance (R13-proven, 114.7 us) --------
__global__ __launch_bounds__(512, 4) void mfma_dist(
    const ushort* __restrict__ CBbf, const ushort* __restrict__ Pbf,
    const float* __restrict__ cnAdj, uint4* __restrict__ top2s)
{
  __shared__ uint4 Tile[4096];                 // 64 KB: P-stage, then 2x32KB dbuf
  __shared__ __align__(16) float cnL[2][64];
  __shared__ ull msh[128][2][2];

  const int bx = blockIdx.x;
  const int h = bx & 3;                 // code quarter
  const int rowbase = (bx >> 2) * 128;
  const int cq0 = h * 2048;
  const int t = threadIdx.x, l = t & 63, w = t >> 6;
  const int rg = w >> 1, cg = w & 1;
  const int c0 = l & 15, g = l >> 4;

  // ---- P prologue: stage 128x256 bf16 (64 KB), swizzle (u + row) & 31 ----
  {
    const ushort* gb = Pbf + ((size_t)rowbase << 8);
    #pragma unroll
    for (int i = 0; i < 8; ++i) {
      int lin = i * 8192 + t * 16;
      int crow = lin >> 9;
      int u = (lin >> 4) & 31;
      GLOAD_LDS16(gb + ((size_t)crow << 8) + (((u - crow) & 31) << 3),
                  (char*)Tile + lin);
    }
  }
  __syncthreads();
  bf16x8 breg[2][8];
  {
    const char* Tb = (const char*)Tile;
    #pragma unroll
    for (int rj = 0; rj < 2; ++rj) {
      const int row = rg * 32 + rj * 16 + c0;
      #pragma unroll
      for (int kk = 0; kk < 8; ++kk)
        breg[rj][kk] = *(const bf16x8*)(Tb + row * 512 + (((kk * 4 + g + row) & 31) << 4));
    }
  }
  __syncthreads();

  const int cl0 = cg * 32 + c0;        // A rows for ci=0 / ci=1
  const int cl1 = cg * 32 + 16 + c0;
  const int ab0 = cl0 * 512;
  const int ab1 = cl1 * 512;
  const int cc0 = cg * 32 + g * 4;     // cnL offsets for ci=0 / ci=1
  const int cc1 = cg * 32 + 16 + g * 4;

  ull k1[2] = {~0ull, ~0ull};
  ull k2[2] = {~0ull, ~0ull};

  // rolling staging pointers: advance 64 codes (32 KB) per chunk
  const ushort* sp[4]; int ldsoff[4];
  #pragma unroll
  for (int i = 0; i < 4; ++i) {
    int lin = i * 8192 + t * 16;
    int crow = lin >> 9;
    int u = (lin >> 4) & 31;
    sp[i] = CBbf + (((size_t)(cq0 + crow)) << 8) + (((u - crow) & 31) << 3);
    ldsoff[i] = lin;
  }
  const float* cnp = cnAdj + cq0 + l;

  #define STAGE(buf)                                                      \
    { char* db = (char*)Tile + (buf) * 32768;                             \
      _Pragma("unroll")                                                   \
      for (int i = 0; i < 4; ++i) {                                       \
        GLOAD_LDS16(sp[i], db + ldsoff[i]);                               \
        sp[i] += 16384;                                                   \
      }                                                                   \
      if (w == 0) GLOAD_LDS4(cnp, (char*)&cnL[buf][0]);                   \
      cnp += 64; }

  STAGE(0);
  __syncthreads();
  for (int ch = 0; ch < 32; ++ch) {
    const int buf = ch & 1;
    if (ch < 31) STAGE(buf ^ 1);
    // acc init = cnAdj (accumulator directly produces v' = cnAdj - 2*dot)
    f32x4 cn0 = *(const f32x4*)&cnL[buf][cc0];
    f32x4 cn1 = *(const f32x4*)&cnL[buf][cc1];
    f32x4 acc[2][2];
    acc[0][0] = cn0; acc[0][1] = cn0;
    acc[1][0] = cn1; acc[1][1] = cn1;
    {
      const char* Tb = (const char*)Tile + buf * 32768;
      int u0 = (g + cl0) & 31;
      int u1 = (g + cl1) & 31;
      #pragma unroll
      for (int kk = 0; kk < 8; ++kk) {
        bf16x8 a0 = *(const bf16x8*)(Tb + ab0 + (u0 << 4));
        bf16x8 a1 = *(const bf16x8*)(Tb + ab1 + (u1 << 4));
        u0 = (u0 + 4) & 31;
        u1 = (u1 + 4) & 31;
        #pragma unroll
        for (int rj = 0; rj < 2; ++rj) {
          acc[0][rj] = __builtin_amdgcn_mfma_f32_16x16x32_bf16(a0, breg[rj][kk], acc[0][rj], 0, 0, 0);
          acc[1][rj] = __builtin_amdgcn_mfma_f32_16x16x32_bf16(a1, breg[rj][kk], acc[1][rj], 0, 0, 0);
        }
      }
    }
    // branchless exact-key fold (u64 lexicographic top-2)
    #pragma unroll
    for (int ci = 0; ci < 2; ++ci) {
      const int cbase = cq0 + ch * 64 + cg * 32 + ci * 16 + g * 4;
      #pragma unroll
      for (int rj = 0; rj < 2; ++rj)
        #pragma unroll
        for (int q = 0; q < 4; ++q) {
          ull key = ((ull)f2u(acc[ci][rj][q]) << 32) | (ull)(cbase + q);
          ull mx = k1[rj] > key ? k1[rj] : key;
          k1[rj] = k1[rj] < key ? k1[rj] : key;
          k2[rj] = k2[rj] < mx ? k2[rj] : mx;
        }
    }
    // bucket flush every 8 chunks (512 codes)
    if ((ch & 7) == 7) {
      #pragma unroll
      for (int rj = 0; rj < 2; ++rj) {
        ull K1 = k1[rj], K2 = k2[rj];
        #pragma unroll
        for (int mask = 16; mask <= 32; mask <<= 1) {
          ull o1 = __shfl_xor(K1, mask);
          ull o2 = __shfl_xor(K2, mask);
          ull mx  = K1 > o1 ? K1 : o1;
          ull mn2 = K2 < o2 ? K2 : o2;
          K1 = K1 < o1 ? K1 : o1;
          K2 = mx < mn2 ? mx : mn2;
        }
        if (g == 0) {
          msh[rg * 32 + rj * 16 + c0][cg][0] = K1;
          msh[rg * 32 + rj * 16 + c0][cg][1] = K2;
        }
        k1[rj] = ~0ull; k2[rj] = ~0ull;
      }
      __syncthreads();
      if (t < 128) {
        ull a1 = msh[t][0][0], a2 = msh[t][0][1];
        ull b1 = msh[t][1][0], b2 = msh[t][1][1];
        ull K1  = a1 < b1 ? a1 : b1;
        ull mx  = a1 > b1 ? a1 : b1;
        ull mn2 = a2 < b2 ? a2 : b2;
        ull K2  = mx < mn2 ? mx : mn2;
        top2s[(size_t)(h * 4 + (ch >> 3)) * NR + rowbase + t] =
            make_uint4((uint32)(K1 >> 32), (uint32)K1, (uint32)(K2 >> 32), (uint32)K2);
      }
    }
    __syncthreads();
  }
  #undef STAGE
}

// ---------------- fused exact rescore + gather + vq_loss (top2s in ws) -------
__global__ __launch_bounds__(256) void rescore_gather(
    const uint4* __restrict__ top2s, const float* __restrict__ P,
    const float* __restrict__ CBF, const float* __restrict__ cnorm,
    float* __restrict__ outq, float* __restrict__ out_ids,
    float* __restrict__ loss)
{
  const int t = threadIdx.x, l = t & 63, w = t >> 6;
  const int row = blockIdx.x * 4 + w;
  float m1 = 3.4e38f, m2 = 3.4e38f;     // shifted-domain values (v' = d2 + VSHIFT)
  uint32 i1 = 0, i2 = 0;
  if (l < NBUCK) {
    uint4 e = top2s[(size_t)l * NR + row];
    m1 = u2f(e.x); i1 = e.y & 8191u;
    m2 = u2f(e.z); i2 = e.w & 8191u;
  }
  float rm = m1;
  #pragma unroll
  for (int mask = 1; mask < 64; mask <<= 1) rm = fminf(rm, __shfl_xor(rm, mask));
  const float thr = rm + DELTA;         // shift cancels in the comparison
  ull qm1 = __ballot(l < NBUCK && m1 <= thr);
  ull qm2 = __ballot(l < NBUCK && m2 <= thr);
  float4 p = *(const float4*)&P[(size_t)row * ED + l * 4];
  double bd = 1e300; int bi = 0x7fffffff;
  #pragma unroll
  for (int cand = 0; cand < 2; ++cand) {
    ull qm = cand ? qm2 : qm1;
    uint32 myi = cand ? i2 : i1;
    while (qm) {
      int b = __ffsll(qm) - 1; qm &= qm - 1;
      int idx = __shfl((int)myi, b);
      const float4 c = *(const float4*)&CBF[(size_t)idx * ED + l * 4];
      double s = (double)p.x * c.x + (double)p.y * c.y + (double)p.z * c.z + (double)p.w * c.w;
      #pragma unroll
      for (int mask = 1; mask < 64; mask <<= 1) s += __shfl_xor(s, mask);
      double d2 = (double)cnorm[idx] - 2.0 * s;
      if (d2 < bd || (d2 == bd && idx < bi)) { bd = d2; bi = idx; }
    }
  }
  // all lanes hold bi: gather CB[bi], write quantized, accumulate loss
  float4 q = *(const float4*)&CBF[(size_t)bi * ED + l * 4];
  *(float4*)&outq[(size_t)row * ED + l * 4] = q;
  float dx = p.x - q.x, dy = p.y - q.y, dz = p.z - q.z, dw = p.w - q.w;
  float sl = dx * dx + dy * dy + dz * dz + dw * dw;
  #pragma unroll
  for (int off = 32; off; off >>= 1) sl += __shfl_down(sl, off, 64);
  __shared__ float partial[4];
  if (l == 0) {
    partial[w] = sl;
    out_ids[row] = (float)bi;
  }
  __syncthreads();
  if (t == 0) {
    float tot = partial[0] + partial[1] + partial[2] + partial[3];
    atomicAdd(loss, tot * (1.25f / ((float)NR * (float)ED)));
  }
}

// ---------------- fallback: rescore (ids only) ----------------
__global__ __launch_bounds__(256) void rescore_kernel(
    const uint4* __restrict__ top2s, const float* __restrict__ P,
    const float* __restrict__ CBF, const float* __restrict__ cnorm,
    int* __restrict__ ids, float* __restrict__ out_ids)
{
  const int t = threadIdx.x, l = t & 63, w = t >> 6;
  const int row = blockIdx.x * 4 + w;
  float m1 = 3.4e38f, m2 = 3.4e38f;
  uint32 i1 = 0, i2 = 0;
  if (l < NBUCK) {
    uint4 e = top2s[(size_t)l * NR + row];
    m1 = u2f(e.x); i1 = e.y & 8191u;
    m2 = u2f(e.z); i2 = e.w & 8191u;
  }
  float rm = m1;
  #pragma unroll
  for (int mask = 1; mask < 64; mask <<= 1) rm = fminf(rm, __shfl_xor(rm, mask));
  const float thr = rm + DELTA;
  ull qm1 = __ballot(l < NBUCK && m1 <= thr);
  ull qm2 = __ballot(l < NBUCK && m2 <= thr);
  float4 p = *(const float4*)&P[(size_t)row * ED + l * 4];
  double bd = 1e300; int bi = 0x7fffffff;
  #pragma unroll
  for (int cand = 0; cand < 2; ++cand) {
    ull qm = cand ? qm2 : qm1;
    uint32 myi = cand ? i2 : i1;
    while (qm) {
      int b = __ffsll(qm) - 1; qm &= qm - 1;
      int idx = __shfl((int)myi, b);
      const float4 c = *(const float4*)&CBF[(size_t)idx * ED + l * 4];
      double s = (double)p.x * c.x + (double)p.y * c.y + (double)p.z * c.z + (double)p.w * c.w;
      #pragma unroll
      for (int mask = 1; mask < 64; mask <<= 1) s += __shfl_xor(s, mask);
      double d2 = (double)cnorm[idx] - 2.0 * s;
      if (d2 < bd || (d2 == bd && idx < bi)) { bd = d2; bi = idx; }
    }
  }
  if (l == 0) {
    ids[row] = bi;
    out_ids[row] = (float)bi;
  }
}

// ---------------- fallback: gather quantized + vq_loss ----------------
__global__ __launch_bounds__(256) void gather_loss(
    const float* __restrict__ P, const float* __restrict__ CB,
    const int* __restrict__ ids, float* __restrict__ outq,
    float* __restrict__ loss)
{
  const int t = threadIdx.x, lane = t & 63, w = t >> 6;
  const int row = blockIdx.x * 4 + w;
  const int id = ids[row];
  float4 q = *(const float4*)&CB[(size_t)id * ED + lane * 4];
  float4 p = *(const float4*)&P[(size_t)row * ED + lane * 4];
  *(float4*)&outq[(size_t)row * ED + lane * 4] = q;
  float dx = p.x - q.x, dy = p.y - q.y, dz = p.z - q.z, dw = p.w - q.w;
  float s = dx * dx + dy * dy + dz * dz + dw * dw;
  #pragma unroll
  for (int off = 32; off; off >>= 1) s += __shfl_down(s, off, 64);
  __shared__ float partial[4];
  if (lane == 0) partial[w] = s;
  __syncthreads();
  if (t == 0){
    float tot = partial[0] + partial[1] + partial[2] + partial[3];
    atomicAdd(loss, tot * (1.25f / ((float)NR * (float)ED)));
  }
}

extern "C" void kernel_launch(void* const* d_in, const int* in_sizes, int n_in,
                              void* d_out, int out_size, void* d_ws, size_t ws_size,
                              hipStream_t stream) {
    const float* values = (const float*)d_in[0];   // [8,2048,1024]
    const float* W      = (const float*)d_in[1];   // [256,1024]
    const float* bias   = (const float*)d_in[2];   // [256]
    const float* CB     = (const float*)d_in[3];   // [8192,256]

    float* out      = (float*)d_out;
    float* out_q    = out;                                  // NR*ED (16 MB)
    float* out_ids  = out + (size_t)NR * ED;                // NR
    float* out_loss = out_ids + NR;                         // 1

    // ws layout
    float*  proj  = (float*)d_ws;                           // 16 MB
    float*  cnorm = proj + (size_t)NR * ED;                 // 32 KB
    float*  cnAdj = cnorm + KC;                             // 32 KB
    ushort* CBbf  = (ushort*)(cnAdj + KC);                  // 4 MB
    int*    ids   = (int*)(CBbf + (size_t)KC * ED);         // 64 KB
    ushort* Whi   = (ushort*)(ids + NR);                    // 512 KB
    ushort* Wlo   = Whi + (size_t)ED * VD;                  // 512 KB
    uint4*  top2s_ws = (uint4*)(Wlo + (size_t)ED * VD);     // 4 MB
    size_t  need  = (size_t)((char*)(top2s_ws + (size_t)NBUCK * NR) - (char*)d_ws);
    const bool fuse = ws_size >= need;

    // If ws can't hold top2s, fall back to the out_q-scratch layout:
    //   [0, 4MB) of out_q: top2s ; [4MB,12MB): Pbf (always in out_q)
    uint4*  top2s = fuse ? top2s_ws : (uint4*)out_q;
    ushort* Pbf   = (ushort*)(out_q + (size_t)NBUCK * NR * 4);  // +4MB in floats

    hipMemsetAsync(out_loss, 0, sizeof(float), stream);
    wconv_kernel<<<ED * VD / (256 * 8), 256, 0, stream>>>(W, Whi, Wlo);
    cnormbf_kernel<<<KC / 4, 256, 0, stream>>>(CB, cnorm, cnAdj, CBbf);
    proj_mfma<<<dim3(NR / 128, ED / 128), 512, 0, stream>>>(values, Whi, Wlo, bias, proj, Pbf);
    mfma_dist<<<512, 512, 0, stream>>>(CBbf, Pbf, cnAdj, top2s);
    if (fuse) {
      rescore_gather<<<NR / 4, 256, 0, stream>>>(top2s, proj, CB, cnorm,
                                                 out_q, out_ids, out_loss);
    } else {
      rescore_kernel<<<NR / 4, 256, 0, stream>>>(top2s, proj, CB, cnorm, ids, out_ids);
      gather_loss<<<NR / 4, 256, 0, stream>>>(proj, CB, ids, out_q, out_loss);
    }
}

// Round 16
// 206.621 us; speedup vs baseline: 1.1351x; 1.0194x over previous
//
#include <hip/hip_runtime.h>

typedef __attribute__((ext_vector_type(8))) short bf16x8;
typedef __attribute__((ext_vector_type(4))) float f32x4;
typedef unsigned int uint32;
typedef unsigned long long ull;

#define NR 16384   // B*S rows
#define VD 1024    // value dim
#define ED 256     // embed dim
#define KC 8192    // codebook size
#define NBUCK 16   // top2 buckets per row (4 quarters x 4)
#define DELTA 2.0f // rescore margin (>= 2*max bf16 d2 noise ~0.9)
#define VSHIFT 128.0f // positivity shift: d2_rel min ~ +78 >> -128

__device__ __forceinline__ uint32 f2u(float f){ return __float_as_uint(f); }
__device__ __forceinline__ float u2f(uint32 u){ return __uint_as_float(u); }

// pack two f32 -> two bf16 (RNE) into one uint (lo16 = first elem)
__device__ __forceinline__ uint32 pkbf(float lo, float hi){
  uint32 a = __float_as_uint(lo); a += 0x7fffu + ((a >> 16) & 1u);
  uint32 b = __float_as_uint(hi); b += 0x7fffu + ((b >> 16) & 1u);
  return (a >> 16) | (b & 0xffff0000u);
}

#define GLOAD_LDS16(g, l) __builtin_amdgcn_global_load_lds( \
    (const __attribute__((address_space(1))) void*)(g),     \
    (__attribute__((address_space(3))) void*)(l), 16, 0, 0)
#define GLOAD_LDS4(g, l) __builtin_amdgcn_global_load_lds(  \
    (const __attribute__((address_space(1))) void*)(g),     \
    (__attribute__((address_space(3))) void*)(l), 4, 0, 0)

// ---------------- W f32 -> (hi trunc-bf16, lo RNE-bf16 of residual) ----------
__global__ __launch_bounds__(256) void wconv_kernel(
    const float* __restrict__ W, ushort* __restrict__ Whi, ushort* __restrict__ Wlo)
{
  const int idx = (blockIdx.x * 256 + threadIdx.x) * 8;
  float4 a = *(const float4*)(W + idx);
  float4 b = *(const float4*)(W + idx + 4);
  uint32 h01 = (f2u(a.x) >> 16) | (f2u(a.y) & 0xffff0000u);
  uint32 h23 = (f2u(a.z) >> 16) | (f2u(a.w) & 0xffff0000u);
  uint32 h45 = (f2u(b.x) >> 16) | (f2u(b.y) & 0xffff0000u);
  uint32 h67 = (f2u(b.z) >> 16) | (f2u(b.w) & 0xffff0000u);
  float r0 = a.x - u2f(f2u(a.x) & 0xffff0000u);
  float r1 = a.y - u2f(f2u(a.y) & 0xffff0000u);
  float r2 = a.z - u2f(f2u(a.z) & 0xffff0000u);
  float r3 = a.w - u2f(f2u(a.w) & 0xffff0000u);
  float r4 = b.x - u2f(f2u(b.x) & 0xffff0000u);
  float r5 = b.y - u2f(f2u(b.y) & 0xffff0000u);
  float r6 = b.z - u2f(f2u(b.z) & 0xffff0000u);
  float r7 = b.w - u2f(f2u(b.w) & 0xffff0000u);
  *(uint4*)(Whi + idx) = make_uint4(h01, h23, h45, h67);
  *(uint4*)(Wlo + idx) = make_uint4(pkbf(r0,r1), pkbf(r2,r3), pkbf(r4,r5), pkbf(r6,r7));
}

// ---------------- projection via split-bf16 MFMA (3-term, ~f32 exact) --------
__global__ __launch_bounds__(512) void proj_mfma(
    const float* __restrict__ V, const ushort* __restrict__ WhiG,
    const ushort* __restrict__ WloG, const float* __restrict__ bias,
    float* __restrict__ C, ushort* __restrict__ Pbf)
{
  __shared__ __align__(16) char lds[128 * 132 * 4];  // 67584 B; dbuf in first 64K
  const int rowbase = blockIdx.x * 128;
  const int colbase = blockIdx.y * 128;
  const int t = threadIdx.x, l = t & 63, w = t >> 6;
  const int c0 = l & 15, g = l >> 4;
  const int rg = w >> 2, cg = w & 3;

  const int srow = t >> 2, sq = t & 3;
  const float* aSrc = V + (size_t)(rowbase + srow) * VD + sq * 8;
  const int wu0 = (sq - (srow >> 3)) & 3;
  const ushort* whSrc = WhiG + (size_t)(colbase + srow) * VD + wu0 * 8;
  const ushort* wlSrc = WloG + (size_t)(colbase + srow) * VD + wu0 * 8;
  const int awOff = srow * 64 + (((sq + (srow >> 3)) & 3) << 4);
  char* wdst = lds + 16384 + (size_t)w * 1024;

  float4 bv[2];
  bv[0] = *(const float4*)&bias[colbase + cg * 32 + g * 4];
  bv[1] = *(const float4*)&bias[colbase + cg * 32 + 16 + g * 4];

  int vOff[4], wOff[2];
  #pragma unroll
  for (int bi = 0; bi < 4; ++bi) {
    int r = rg * 64 + bi * 16 + c0;
    vOff[bi] = r * 64 + (((g + (r >> 3)) & 3) << 4);
  }
  #pragma unroll
  for (int aj = 0; aj < 2; ++aj) {
    int r = cg * 32 + aj * 16 + c0;
    wOff[aj] = r * 64 + (((g + (r >> 3)) & 3) << 4);
  }

  f32x4 acc[2][4];
  #pragma unroll
  for (int aj = 0; aj < 2; ++aj)
    #pragma unroll
    for (int bi = 0; bi < 4; ++bi) acc[aj][bi] = (f32x4){0.f,0.f,0.f,0.f};

  float4 fa0, fa1;
  #define LOAD_A(ch)  { fa0 = *(const float4*)(aSrc + (ch) * 32); \
                        fa1 = *(const float4*)(aSrc + (ch) * 32 + 4); }
  #define STAGE_W(ch, buf) { \
    GLOAD_LDS16(whSrc + (ch) * 32, wdst + (buf) * 32768);        \
    GLOAD_LDS16(wlSrc + (ch) * 32, wdst + (buf) * 32768 + 8192); }
  #define CONV_WRITE(buf) { \
    uint32 h01 = (f2u(fa0.x)>>16)|(f2u(fa0.y)&0xffff0000u); \
    uint32 h23 = (f2u(fa0.z)>>16)|(f2u(fa0.w)&0xffff0000u); \
    uint32 h45 = (f2u(fa1.x)>>16)|(f2u(fa1.y)&0xffff0000u); \
    uint32 h67 = (f2u(fa1.z)>>16)|(f2u(fa1.w)&0xffff0000u); \
    float r0 = fa0.x - u2f(f2u(fa0.x)&0xffff0000u); \
    float r1 = fa0.y - u2f(f2u(fa0.y)&0xffff0000u); \
    float r2 = fa0.z - u2f(f2u(fa0.z)&0xffff0000u); \
    float r3 = fa0.w - u2f(f2u(fa0.w)&0xffff0000u); \
    float r4 = fa1.x - u2f(f2u(fa1.x)&0xffff0000u); \
    float r5 = fa1.y - u2f(f2u(fa1.y)&0xffff0000u); \
    float r6 = fa1.z - u2f(f2u(fa1.z)&0xffff0000u); \
    float r7 = fa1.w - u2f(f2u(fa1.w)&0xffff0000u); \
    *(uint4*)(lds + (buf)*32768 + awOff) = make_uint4(h01,h23,h45,h67); \
    *(uint4*)(lds + (buf)*32768 + 8192 + awOff) = \
        make_uint4(pkbf(r0,r1), pkbf(r2,r3), pkbf(r4,r5), pkbf(r6,r7)); }
  #define COMPUTE(buf) { \
    const char* Bq = lds + (buf) * 32768; \
    bf16x8 vh[4], vl[4], wh[2], wl[2]; \
    _Pragma("unroll") \
    for (int bi = 0; bi < 4; ++bi) { \
      vh[bi] = *(const bf16x8*)(Bq + vOff[bi]); \
      vl[bi] = *(const bf16x8*)(Bq + 8192 + vOff[bi]); } \
    _Pragma("unroll") \
    for (int aj = 0; aj < 2; ++aj) { \
      wh[aj] = *(const bf16x8*)(Bq + 16384 + wOff[aj]); \
      wl[aj] = *(const bf16x8*)(Bq + 24576 + wOff[aj]); } \
    _Pragma("unroll") \
    for (int aj = 0; aj < 2; ++aj) \
      _Pragma("unroll") \
      for (int bi = 0; bi < 4; ++bi) { \
        acc[aj][bi] = __builtin_amdgcn_mfma_f32_16x16x32_bf16(wh[aj], vh[bi], acc[aj][bi], 0, 0, 0); \
        acc[aj][bi] = __builtin_amdgcn_mfma_f32_16x16x32_bf16(wh[aj], vl[bi], acc[aj][bi], 0, 0, 0); \
        acc[aj][bi] = __builtin_amdgcn_mfma_f32_16x16x32_bf16(wl[aj], vh[bi], acc[aj][bi], 0, 0, 0); } }

  LOAD_A(0); STAGE_W(0, 0);
  CONV_WRITE(0);
  __syncthreads();
  int buf = 0;
  for (int ch = 0; ch < 32; ++ch) {
    if (ch < 31) { LOAD_A(ch + 1); STAGE_W(ch + 1, buf ^ 1); }
    COMPUTE(buf);
    if (ch < 31) CONV_WRITE(buf ^ 1);
    __syncthreads();
    buf ^= 1;
  }
  #undef LOAD_A
  #undef STAGE_W
  #undef CONV_WRITE
  #undef COMPUTE

  float* Cs = (float*)lds;
  #pragma unroll
  for (int aj = 0; aj < 2; ++aj)
    #pragma unroll
    for (int bi = 0; bi < 4; ++bi) {
      int prow = rg * 64 + bi * 16 + c0;
      int pcol = cg * 32 + aj * 16 + g * 4;
      f32x4 v = acc[aj][bi];
      float4 o = make_float4(v[0] + bv[aj].x, v[1] + bv[aj].y,
                             v[2] + bv[aj].z, v[3] + bv[aj].w);
      *(float4*)&Cs[prow * 132 + pcol] = o;
    }
  __syncthreads();
  {
    const int row = t >> 2, qd = t & 3;
    const float* src = &Cs[row * 132 + qd * 32];
    float* cdst = &C[(size_t)(rowbase + row) * ED + colbase + qd * 32];
    float4 vv[8];
    #pragma unroll
    for (int i = 0; i < 8; ++i) vv[i] = *(const float4*)(src + i * 4);
    #pragma unroll
    for (int i = 0; i < 8; ++i) *(float4*)(cdst + i * 4) = vv[i];
    uint4 pk[4];
    #pragma unroll
    for (int i = 0; i < 4; ++i)
      pk[i] = make_uint4(pkbf(vv[2*i].x, vv[2*i].y), pkbf(vv[2*i].z, vv[2*i].w),
                         pkbf(vv[2*i+1].x, vv[2*i+1].y), pkbf(vv[2*i+1].z, vv[2*i+1].w));
    uint4* pdst = (uint4*)&Pbf[(size_t)(rowbase + row) * ED + colbase + qd * 32];
    #pragma unroll
    for (int i = 0; i < 4; ++i) pdst[i] = pk[i];
  }
}

// ---------------- codebook norms (f64) + bf16(-2c) emission ----------------
__global__ __launch_bounds__(256) void cnormbf_kernel(
    const float* __restrict__ CB, float* __restrict__ cnorm,
    float* __restrict__ cnAdj, ushort* __restrict__ CBbf)
{
  const int t = threadIdx.x, lane = t & 63, w = t >> 6;
  const int code = blockIdx.x * 4 + w;
  float4 c = *(const float4*)&CB[(size_t)code * ED + lane * 4];
  uint2 pk = make_uint2(pkbf(-2.f * c.x, -2.f * c.y), pkbf(-2.f * c.z, -2.f * c.w));
  *(uint2*)&CBbf[(size_t)code * ED + lane * 4] = pk;
  double s = (double)c.x * c.x + (double)c.y * c.y + (double)c.z * c.z + (double)c.w * c.w;
  #pragma unroll
  for (int off = 32; off; off >>= 1) s += __shfl_down(s, off, 64);
  if (lane == 0) {
    cnorm[code] = (float)s;
    cnAdj[code] = (float)s + VSHIFT;
  }
}

// ---------------- code-streaming MFMA distance (conflict-free swizzle) -------
// R13 structure; LDS unit swizzle changed (u+row)&31 -> (u+4*row)&31 so the
// 64-lane ds_read_b128 pattern hits each 16B unit exactly 2x (2-way = free)
// instead of 4-way. Applied to BOTH staging source and all reads (rule #21).
__global__ __launch_bounds__(512, 4) void mfma_dist(
    const ushort* __restrict__ CBbf, const ushort* __restrict__ Pbf,
    const float* __restrict__ cnAdj, uint4* __restrict__ top2s)
{
  __shared__ uint4 Tile[4096];                 // 64 KB: P-stage, then 2x32KB dbuf
  __shared__ __align__(16) float cnL[2][64];
  __shared__ ull msh[128][2][2];

  const int bx = blockIdx.x;
  const int h = bx & 3;                 // code quarter
  const int rowbase = (bx >> 2) * 128;
  const int cq0 = h * 2048;
  const int t = threadIdx.x, l = t & 63, w = t >> 6;
  const int rg = w >> 1, cg = w & 1;
  const int c0 = l & 15, g = l >> 4;

  // ---- P prologue: stage 128x256 bf16 (64 KB), swizzle (u + 4*row) & 31 ----
  {
    const ushort* gb = Pbf + ((size_t)rowbase << 8);
    #pragma unroll
    for (int i = 0; i < 8; ++i) {
      int lin = i * 8192 + t * 16;
      int crow = lin >> 9;
      int u = (lin >> 4) & 31;
      GLOAD_LDS16(gb + ((size_t)crow << 8) + (((u - 4 * crow) & 31) << 3),
                  (char*)Tile + lin);
    }
  }
  __syncthreads();
  bf16x8 breg[2][8];
  {
    const char* Tb = (const char*)Tile;
    #pragma unroll
    for (int rj = 0; rj < 2; ++rj) {
      const int row = rg * 32 + rj * 16 + c0;
      #pragma unroll
      for (int kk = 0; kk < 8; ++kk)
        breg[rj][kk] = *(const bf16x8*)(Tb + row * 512 + (((kk * 4 + g + 4 * row) & 31) << 4));
    }
  }
  __syncthreads();

  const int cl0 = cg * 32 + c0;        // A rows for ci=0 / ci=1
  const int cl1 = cg * 32 + 16 + c0;
  const int ab0 = cl0 * 512;
  const int ab1 = cl1 * 512;
  const int cc0 = cg * 32 + g * 4;     // cnL offsets for ci=0 / ci=1
  const int cc1 = cg * 32 + 16 + g * 4;

  ull k1[2] = {~0ull, ~0ull};
  ull k2[2] = {~0ull, ~0ull};

  // rolling staging pointers: advance 64 codes (32 KB) per chunk
  const ushort* sp[4]; int ldsoff[4];
  #pragma unroll
  for (int i = 0; i < 4; ++i) {
    int lin = i * 8192 + t * 16;
    int crow = lin >> 9;
    int u = (lin >> 4) & 31;
    sp[i] = CBbf + (((size_t)(cq0 + crow)) << 8) + (((u - 4 * crow) & 31) << 3);
    ldsoff[i] = lin;
  }
  const float* cnp = cnAdj + cq0 + l;

  #define STAGE(buf)                                                      \
    { char* db = (char*)Tile + (buf) * 32768;                             \
      _Pragma("unroll")                                                   \
      for (int i = 0; i < 4; ++i) {                                       \
        GLOAD_LDS16(sp[i], db + ldsoff[i]);                               \
        sp[i] += 16384;                                                   \
      }                                                                   \
      if (w == 0) GLOAD_LDS4(cnp, (char*)&cnL[buf][0]);                   \
      cnp += 64; }

  STAGE(0);
  __syncthreads();
  for (int ch = 0; ch < 32; ++ch) {
    const int buf = ch & 1;
    if (ch < 31) STAGE(buf ^ 1);
    // acc init = cnAdj (accumulator directly produces v' = cnAdj - 2*dot)
    f32x4 cn0 = *(const f32x4*)&cnL[buf][cc0];
    f32x4 cn1 = *(const f32x4*)&cnL[buf][cc1];
    f32x4 acc[2][2];
    acc[0][0] = cn0; acc[0][1] = cn0;
    acc[1][0] = cn1; acc[1][1] = cn1;
    {
      const char* Tb = (const char*)Tile + buf * 32768;
      int u0 = (g + 4 * cl0) & 31;
      int u1 = (g + 4 * cl1) & 31;
      #pragma unroll
      for (int kk = 0; kk < 8; ++kk) {
        bf16x8 a0 = *(const bf16x8*)(Tb + ab0 + (u0 << 4));
        bf16x8 a1 = *(const bf16x8*)(Tb + ab1 + (u1 << 4));
        u0 = (u0 + 4) & 31;
        u1 = (u1 + 4) & 31;
        #pragma unroll
        for (int rj = 0; rj < 2; ++rj) {
          acc[0][rj] = __builtin_amdgcn_mfma_f32_16x16x32_bf16(a0, breg[rj][kk], acc[0][rj], 0, 0, 0);
          acc[1][rj] = __builtin_amdgcn_mfma_f32_16x16x32_bf16(a1, breg[rj][kk], acc[1][rj], 0, 0, 0);
        }
      }
    }
    // branchless exact-key fold (u64 lexicographic top-2)
    #pragma unroll
    for (int ci = 0; ci < 2; ++ci) {
      const int cbase = cq0 + ch * 64 + cg * 32 + ci * 16 + g * 4;
      #pragma unroll
      for (int rj = 0; rj < 2; ++rj)
        #pragma unroll
        for (int q = 0; q < 4; ++q) {
          ull key = ((ull)f2u(acc[ci][rj][q]) << 32) | (ull)(cbase + q);
          ull mx = k1[rj] > key ? k1[rj] : key;
          k1[rj] = k1[rj] < key ? k1[rj] : key;
          k2[rj] = k2[rj] < mx ? k2[rj] : mx;
        }
    }
    // bucket flush every 8 chunks (512 codes)
    if ((ch & 7) == 7) {
      #pragma unroll
      for (int rj = 0; rj < 2; ++rj) {
        ull K1 = k1[rj], K2 = k2[rj];
        #pragma unroll
        for (int mask = 16; mask <= 32; mask <<= 1) {
          ull o1 = __shfl_xor(K1, mask);
          ull o2 = __shfl_xor(K2, mask);
          ull mx  = K1 > o1 ? K1 : o1;
          ull mn2 = K2 < o2 ? K2 : o2;
          K1 = K1 < o1 ? K1 : o1;
          K2 = mx < mn2 ? mx : mn2;
        }
        if (g == 0) {
          msh[rg * 32 + rj * 16 + c0][cg][0] = K1;
          msh[rg * 32 + rj * 16 + c0][cg][1] = K2;
        }
        k1[rj] = ~0ull; k2[rj] = ~0ull;
      }
      __syncthreads();
      if (t < 128) {
        ull a1 = msh[t][0][0], a2 = msh[t][0][1];
        ull b1 = msh[t][1][0], b2 = msh[t][1][1];
        ull K1  = a1 < b1 ? a1 : b1;
        ull mx  = a1 > b1 ? a1 : b1;
        ull mn2 = a2 < b2 ? a2 : b2;
        ull K2  = mx < mn2 ? mx : mn2;
        top2s[(size_t)(h * 4 + (ch >> 3)) * NR + rowbase + t] =
            make_uint4((uint32)(K1 >> 32), (uint32)K1, (uint32)(K2 >> 32), (uint32)K2);
      }
    }
    __syncthreads();
  }
  #undef STAGE
}

// ---------------- fused exact rescore + gather + vq_loss (top2s in ws) -------
__global__ __launch_bounds__(256) void rescore_gather(
    const uint4* __restrict__ top2s, const float* __restrict__ P,
    const float* __restrict__ CBF, const float* __restrict__ cnorm,
    float* __restrict__ outq, float* __restrict__ out_ids,
    float* __restrict__ loss)
{
  const int t = threadIdx.x, l = t & 63, w = t >> 6;
  const int row = blockIdx.x * 4 + w;
  float m1 = 3.4e38f, m2 = 3.4e38f;     // shifted-domain values (v' = d2 + VSHIFT)
  uint32 i1 = 0, i2 = 0;
  if (l < NBUCK) {
    uint4 e = top2s[(size_t)l * NR + row];
    m1 = u2f(e.x); i1 = e.y & 8191u;
    m2 = u2f(e.z); i2 = e.w & 8191u;
  }
  float rm = m1;
  #pragma unroll
  for (int mask = 1; mask < 64; mask <<= 1) rm = fminf(rm, __shfl_xor(rm, mask));
  const float thr = rm + DELTA;         // shift cancels in the comparison
  ull qm1 = __ballot(l < NBUCK && m1 <= thr);
  ull qm2 = __ballot(l < NBUCK && m2 <= thr);
  float4 p = *(const float4*)&P[(size_t)row * ED + l * 4];
  double bd = 1e300; int bi = 0x7fffffff;
  #pragma unroll
  for (int cand = 0; cand < 2; ++cand) {
    ull qm = cand ? qm2 : qm1;
    uint32 myi = cand ? i2 : i1;
    while (qm) {
      int b = __ffsll(qm) - 1; qm &= qm - 1;
      int idx = __shfl((int)myi, b);
      const float4 c = *(const float4*)&CBF[(size_t)idx * ED + l * 4];
      double s = (double)p.x * c.x + (double)p.y * c.y + (double)p.z * c.z + (double)p.w * c.w;
      #pragma unroll
      for (int mask = 1; mask < 64; mask <<= 1) s += __shfl_xor(s, mask);
      double d2 = (double)cnorm[idx] - 2.0 * s;
      if (d2 < bd || (d2 == bd && idx < bi)) { bd = d2; bi = idx; }
    }
  }
  // all lanes hold bi: gather CB[bi], write quantized, accumulate loss
  float4 q = *(const float4*)&CBF[(size_t)bi * ED + l * 4];
  *(float4*)&outq[(size_t)row * ED + l * 4] = q;
  float dx = p.x - q.x, dy = p.y - q.y, dz = p.z - q.z, dw = p.w - q.w;
  float sl = dx * dx + dy * dy + dz * dz + dw * dw;
  #pragma unroll
  for (int off = 32; off; off >>= 1) sl += __shfl_down(sl, off, 64);
  __shared__ float partial[4];
  if (l == 0) {
    partial[w] = sl;
    out_ids[row] = (float)bi;
  }
  __syncthreads();
  if (t == 0) {
    float tot = partial[0] + partial[1] + partial[2] + partial[3];
    atomicAdd(loss, tot * (1.25f / ((float)NR * (float)ED)));
  }
}

// ---------------- fallback: rescore (ids only) ----------------
__global__ __launch_bounds__(256) void rescore_kernel(
    const uint4* __restrict__ top2s, const float* __restrict__ P,
    const float* __restrict__ CBF, const float* __restrict__ cnorm,
    int* __restrict__ ids, float* __restrict__ out_ids)
{
  const int t = threadIdx.x, l = t & 63, w = t >> 6;
  const int row = blockIdx.x * 4 + w;
  float m1 = 3.4e38f, m2 = 3.4e38f;
  uint32 i1 = 0, i2 = 0;
  if (l < NBUCK) {
    uint4 e = top2s[(size_t)l * NR + row];
    m1 = u2f(e.x); i1 = e.y & 8191u;
    m2 = u2f(e.z); i2 = e.w & 8191u;
  }
  float rm = m1;
  #pragma unroll
  for (int mask = 1; mask < 64; mask <<= 1) rm = fminf(rm, __shfl_xor(rm, mask));
  const float thr = rm + DELTA;
  ull qm1 = __ballot(l < NBUCK && m1 <= thr);
  ull qm2 = __ballot(l < NBUCK && m2 <= thr);
  float4 p = *(const float4*)&P[(size_t)row * ED + l * 4];
  double bd = 1e300; int bi = 0x7fffffff;
  #pragma unroll
  for (int cand = 0; cand < 2; ++cand) {
    ull qm = cand ? qm2 : qm1;
    uint32 myi = cand ? i2 : i1;
    while (qm) {
      int b = __ffsll(qm) - 1; qm &= qm - 1;
      int idx = __shfl((int)myi, b);
      const float4 c = *(const float4*)&CBF[(size_t)idx * ED + l * 4];
      double s = (double)p.x * c.x + (double)p.y * c.y + (double)p.z * c.z + (double)p.w * c.w;
      #pragma unroll
      for (int mask = 1; mask < 64; mask <<= 1) s += __shfl_xor(s, mask);
      double d2 = (double)cnorm[idx] - 2.0 * s;
      if (d2 < bd || (d2 == bd && idx < bi)) { bd = d2; bi = idx; }
    }
  }
  if (l == 0) {
    ids[row] = bi;
    out_ids[row] = (float)bi;
  }
}

// ---------------- fallback: gather quantized + vq_loss ----------------
__global__ __launch_bounds__(256) void gather_loss(
    const float* __restrict__ P, const float* __restrict__ CB,
    const int* __restrict__ ids, float* __restrict__ outq,
    float* __restrict__ loss)
{
  const int t = threadIdx.x, lane = t & 63, w = t >> 6;
  const int row = blockIdx.x * 4 + w;
  const int id = ids[row];
  float4 q = *(const float4*)&CB[(size_t)id * ED + lane * 4];
  float4 p = *(const float4*)&P[(size_t)row * ED + lane * 4];
  *(float4*)&outq[(size_t)row * ED + lane * 4] = q;
  float dx = p.x - q.x, dy = p.y - q.y, dz = p.z - q.z, dw = p.w - q.w;
  float s = dx * dx + dy * dy + dz * dz + dw * dw;
  #pragma unroll
  for (int off = 32; off; off >>= 1) s += __shfl_down(s, off, 64);
  __shared__ float partial[4];
  if (lane == 0) partial[w] = s;
  __syncthreads();
  if (t == 0){
    float tot = partial[0] + partial[1] + partial[2] + partial[3];
    atomicAdd(loss, tot * (1.25f / ((float)NR * (float)ED)));
  }
}

extern "C" void kernel_launch(void* const* d_in, const int* in_sizes, int n_in,
                              void* d_out, int out_size, void* d_ws, size_t ws_size,
                              hipStream_t stream) {
    const float* values = (const float*)d_in[0];   // [8,2048,1024]
    const float* W      = (const float*)d_in[1];   // [256,1024]
    const float* bias   = (const float*)d_in[2];   // [256]
    const float* CB     = (const float*)d_in[3];   // [8192,256]

    float* out      = (float*)d_out;
    float* out_q    = out;                                  // NR*ED (16 MB)
    float* out_ids  = out + (size_t)NR * ED;                // NR
    float* out_loss = out_ids + NR;                         // 1

    // ws layout
    float*  proj  = (float*)d_ws;                           // 16 MB
    float*  cnorm = proj + (size_t)NR * ED;                 // 32 KB
    float*  cnAdj = cnorm + KC;                             // 32 KB
    ushort* CBbf  = (ushort*)(cnAdj + KC);                  // 4 MB
    int*    ids   = (int*)(CBbf + (size_t)KC * ED);         // 64 KB
    ushort* Whi   = (ushort*)(ids + NR);                    // 512 KB
    ushort* Wlo   = Whi + (size_t)ED * VD;                  // 512 KB
    uint4*  top2s_ws = (uint4*)(Wlo + (size_t)ED * VD);     // 4 MB
    size_t  need  = (size_t)((char*)(top2s_ws + (size_t)NBUCK * NR) - (char*)d_ws);
    const bool fuse = ws_size >= need;

    // If ws can't hold top2s, fall back to the out_q-scratch layout:
    //   [0, 4MB) of out_q: top2s ; [4MB,12MB): Pbf (always in out_q)
    uint4*  top2s = fuse ? top2s_ws : (uint4*)out_q;
    ushort* Pbf   = (ushort*)(out_q + (size_t)NBUCK * NR * 4);  // +4MB in floats

    hipMemsetAsync(out_loss, 0, sizeof(float), stream);
    wconv_kernel<<<ED * VD / (256 * 8), 256, 0, stream>>>(W, Whi, Wlo);
    cnormbf_kernel<<<KC / 4, 256, 0, stream>>>(CB, cnorm, cnAdj, CBbf);
    proj_mfma<<<dim3(NR / 128, ED / 128), 512, 0, stream>>>(values, Whi, Wlo, bias, proj, Pbf);
    mfma_dist<<<512, 512, 0, stream>>>(CBbf, Pbf, cnAdj, top2s);
    if (fuse) {
      rescore_gather<<<NR / 4, 256, 0, stream>>>(top2s, proj, CB, cnorm,
                                                 out_q, out_ids, out_loss);
    } else {
      rescore_kernel<<<NR / 4, 256, 0, stream>>>(top2s, proj, CB, cnorm, ids, out_ids);
      gather_loss<<<NR / 4, 256, 0, stream>>>(proj, CB, ids, out_q, out_loss);
    }
}

// Round 17
// 200.635 us; speedup vs baseline: 1.1689x; 1.0298x over previous
//
#include <hip/hip_runtime.h>

typedef __attribute__((ext_vector_type(8))) short bf16x8;
typedef __attribute__((ext_vector_type(4))) float f32x4;
typedef unsigned int uint32;
typedef unsigned long long ull;

#define NR 16384   // B*S rows
#define VD 1024    // value dim
#define ED 256     // embed dim
#define KC 8192    // codebook size
#define NBUCK 16   // top2 buckets per row (4 quarters x 4)
#define DELTA 2.0f // rescore margin (>= 2*max bf16 d2 noise ~0.9)
#define VSHIFT 128.0f // positivity shift: d2_rel min ~ +78 >> -128

__device__ __forceinline__ uint32 f2u(float f){ return __float_as_uint(f); }
__device__ __forceinline__ float u2f(uint32 u){ return __uint_as_float(u); }

// pack two f32 -> two bf16 (RNE) into one uint (lo16 = first elem)
__device__ __forceinline__ uint32 pkbf(float lo, float hi){
  uint32 a = __float_as_uint(lo); a += 0x7fffu + ((a >> 16) & 1u);
  uint32 b = __float_as_uint(hi); b += 0x7fffu + ((b >> 16) & 1u);
  return (a >> 16) | (b & 0xffff0000u);
}

#define GLOAD_LDS16(g, l) __builtin_amdgcn_global_load_lds( \
    (const __attribute__((address_space(1))) void*)(g),     \
    (__attribute__((address_space(3))) void*)(l), 16, 0, 0)
#define GLOAD_LDS4(g, l) __builtin_amdgcn_global_load_lds(  \
    (const __attribute__((address_space(1))) void*)(g),     \
    (__attribute__((address_space(3))) void*)(l), 4, 0, 0)

// ------- fused prep: W split-bf16 + codebook norms/bf16(-2c) + loss init -----
// grid 2048 blocks: all do the cnorm part (4 codes each); blocks 0..127 also
// convert W (128*2048 = ED*VD elems at 8/thread); block 0 inits loss.
__global__ __launch_bounds__(256) void prep_kernel(
    const float* __restrict__ W, const float* __restrict__ CB,
    float* __restrict__ cnorm, float* __restrict__ cnAdj,
    ushort* __restrict__ CBbf, ushort* __restrict__ Whi,
    ushort* __restrict__ Wlo, float* __restrict__ loss)
{
  const int t = threadIdx.x, lane = t & 63, w = t >> 6;
  if (blockIdx.x == 0 && t == 0) *loss = 0.f;
  // ---- cnorm part ----
  {
    const int code = blockIdx.x * 4 + w;
    float4 c = *(const float4*)&CB[(size_t)code * ED + lane * 4];
    uint2 pk = make_uint2(pkbf(-2.f * c.x, -2.f * c.y), pkbf(-2.f * c.z, -2.f * c.w));
    *(uint2*)&CBbf[(size_t)code * ED + lane * 4] = pk;
    double s = (double)c.x * c.x + (double)c.y * c.y + (double)c.z * c.z + (double)c.w * c.w;
    #pragma unroll
    for (int off = 32; off; off >>= 1) s += __shfl_down(s, off, 64);
    if (lane == 0) {
      cnorm[code] = (float)s;
      cnAdj[code] = (float)s + VSHIFT;
    }
  }
  // ---- wconv part (first 128 blocks) ----
  if (blockIdx.x < 128) {
    const int idx = (blockIdx.x * 256 + t) * 8;
    float4 a = *(const float4*)(W + idx);
    float4 b = *(const float4*)(W + idx + 4);
    uint32 h01 = (f2u(a.x) >> 16) | (f2u(a.y) & 0xffff0000u);
    uint32 h23 = (f2u(a.z) >> 16) | (f2u(a.w) & 0xffff0000u);
    uint32 h45 = (f2u(b.x) >> 16) | (f2u(b.y) & 0xffff0000u);
    uint32 h67 = (f2u(b.z) >> 16) | (f2u(b.w) & 0xffff0000u);
    float r0 = a.x - u2f(f2u(a.x) & 0xffff0000u);
    float r1 = a.y - u2f(f2u(a.y) & 0xffff0000u);
    float r2 = a.z - u2f(f2u(a.z) & 0xffff0000u);
    float r3 = a.w - u2f(f2u(a.w) & 0xffff0000u);
    float r4 = b.x - u2f(f2u(b.x) & 0xffff0000u);
    float r5 = b.y - u2f(f2u(b.y) & 0xffff0000u);
    float r6 = b.z - u2f(f2u(b.z) & 0xffff0000u);
    float r7 = b.w - u2f(f2u(b.w) & 0xffff0000u);
    *(uint4*)(Whi + idx) = make_uint4(h01, h23, h45, h67);
    *(uint4*)(Wlo + idx) = make_uint4(pkbf(r0,r1), pkbf(r2,r3), pkbf(r4,r5), pkbf(r6,r7));
  }
}

// ---------------- projection via split-bf16 MFMA (3-term, ~f32 exact) --------
// __launch_bounds__(512, 4): cap VGPR at 128 -> 2 blocks/CU (LDS 2x67.5 <= 160K).
__global__ __launch_bounds__(512, 4) void proj_mfma(
    const float* __restrict__ V, const ushort* __restrict__ WhiG,
    const ushort* __restrict__ WloG, const float* __restrict__ bias,
    float* __restrict__ C, ushort* __restrict__ Pbf)
{
  __shared__ __align__(16) char lds[128 * 132 * 4];  // 67584 B; dbuf in first 64K
  const int rowbase = blockIdx.x * 128;
  const int colbase = blockIdx.y * 128;
  const int t = threadIdx.x, l = t & 63, w = t >> 6;
  const int c0 = l & 15, g = l >> 4;
  const int rg = w >> 2, cg = w & 3;

  const int srow = t >> 2, sq = t & 3;
  const float* aSrc = V + (size_t)(rowbase + srow) * VD + sq * 8;
  const int wu0 = (sq - (srow >> 3)) & 3;
  const ushort* whSrc = WhiG + (size_t)(colbase + srow) * VD + wu0 * 8;
  const ushort* wlSrc = WloG + (size_t)(colbase + srow) * VD + wu0 * 8;
  const int awOff = srow * 64 + (((sq + (srow >> 3)) & 3) << 4);
  char* wdst = lds + 16384 + (size_t)w * 1024;

  float4 bv[2];
  bv[0] = *(const float4*)&bias[colbase + cg * 32 + g * 4];
  bv[1] = *(const float4*)&bias[colbase + cg * 32 + 16 + g * 4];

  int vOff[4], wOff[2];
  #pragma unroll
  for (int bi = 0; bi < 4; ++bi) {
    int r = rg * 64 + bi * 16 + c0;
    vOff[bi] = r * 64 + (((g + (r >> 3)) & 3) << 4);
  }
  #pragma unroll
  for (int aj = 0; aj < 2; ++aj) {
    int r = cg * 32 + aj * 16 + c0;
    wOff[aj] = r * 64 + (((g + (r >> 3)) & 3) << 4);
  }

  f32x4 acc[2][4];
  #pragma unroll
  for (int aj = 0; aj < 2; ++aj)
    #pragma unroll
    for (int bi = 0; bi < 4; ++bi) acc[aj][bi] = (f32x4){0.f,0.f,0.f,0.f};

  float4 fa0, fa1;
  #define LOAD_A(ch)  { fa0 = *(const float4*)(aSrc + (ch) * 32); \
                        fa1 = *(const float4*)(aSrc + (ch) * 32 + 4); }
  #define STAGE_W(ch, buf) { \
    GLOAD_LDS16(whSrc + (ch) * 32, wdst + (buf) * 32768);        \
    GLOAD_LDS16(wlSrc + (ch) * 32, wdst + (buf) * 32768 + 8192); }
  #define CONV_WRITE(buf) { \
    uint32 h01 = (f2u(fa0.x)>>16)|(f2u(fa0.y)&0xffff0000u); \
    uint32 h23 = (f2u(fa0.z)>>16)|(f2u(fa0.w)&0xffff0000u); \
    uint32 h45 = (f2u(fa1.x)>>16)|(f2u(fa1.y)&0xffff0000u); \
    uint32 h67 = (f2u(fa1.z)>>16)|(f2u(fa1.w)&0xffff0000u); \
    float r0 = fa0.x - u2f(f2u(fa0.x)&0xffff0000u); \
    float r1 = fa0.y - u2f(f2u(fa0.y)&0xffff0000u); \
    float r2 = fa0.z - u2f(f2u(fa0.z)&0xffff0000u); \
    float r3 = fa0.w - u2f(f2u(fa0.w)&0xffff0000u); \
    float r4 = fa1.x - u2f(f2u(fa1.x)&0xffff0000u); \
    float r5 = fa1.y - u2f(f2u(fa1.y)&0xffff0000u); \
    float r6 = fa1.z - u2f(f2u(fa1.z)&0xffff0000u); \
    float r7 = fa1.w - u2f(f2u(fa1.w)&0xffff0000u); \
    *(uint4*)(lds + (buf)*32768 + awOff) = make_uint4(h01,h23,h45,h67); \
    *(uint4*)(lds + (buf)*32768 + 8192 + awOff) = \
        make_uint4(pkbf(r0,r1), pkbf(r2,r3), pkbf(r4,r5), pkbf(r6,r7)); }
  #define COMPUTE(buf) { \
    const char* Bq = lds + (buf) * 32768; \
    bf16x8 vh[4], vl[4], wh[2], wl[2]; \
    _Pragma("unroll") \
    for (int bi = 0; bi < 4; ++bi) { \
      vh[bi] = *(const bf16x8*)(Bq + vOff[bi]); \
      vl[bi] = *(const bf16x8*)(Bq + 8192 + vOff[bi]); } \
    _Pragma("unroll") \
    for (int aj = 0; aj < 2; ++aj) { \
      wh[aj] = *(const bf16x8*)(Bq + 16384 + wOff[aj]); \
      wl[aj] = *(const bf16x8*)(Bq + 24576 + wOff[aj]); } \
    _Pragma("unroll") \
    for (int aj = 0; aj < 2; ++aj) \
      _Pragma("unroll") \
      for (int bi = 0; bi < 4; ++bi) { \
        acc[aj][bi] = __builtin_amdgcn_mfma_f32_16x16x32_bf16(wh[aj], vh[bi], acc[aj][bi], 0, 0, 0); \
        acc[aj][bi] = __builtin_amdgcn_mfma_f32_16x16x32_bf16(wh[aj], vl[bi], acc[aj][bi], 0, 0, 0); \
        acc[aj][bi] = __builtin_amdgcn_mfma_f32_16x16x32_bf16(wl[aj], vh[bi], acc[aj][bi], 0, 0, 0); } }

  LOAD_A(0); STAGE_W(0, 0);
  CONV_WRITE(0);
  __syncthreads();
  int buf = 0;
  for (int ch = 0; ch < 32; ++ch) {
    if (ch < 31) { LOAD_A(ch + 1); STAGE_W(ch + 1, buf ^ 1); }
    COMPUTE(buf);
    if (ch < 31) CONV_WRITE(buf ^ 1);
    __syncthreads();
    buf ^= 1;
  }
  #undef LOAD_A
  #undef STAGE_W
  #undef CONV_WRITE
  #undef COMPUTE

  float* Cs = (float*)lds;
  #pragma unroll
  for (int aj = 0; aj < 2; ++aj)
    #pragma unroll
    for (int bi = 0; bi < 4; ++bi) {
      int prow = rg * 64 + bi * 16 + c0;
      int pcol = cg * 32 + aj * 16 + g * 4;
      f32x4 v = acc[aj][bi];
      float4 o = make_float4(v[0] + bv[aj].x, v[1] + bv[aj].y,
                             v[2] + bv[aj].z, v[3] + bv[aj].w);
      *(float4*)&Cs[prow * 132 + pcol] = o;
    }
  __syncthreads();
  {
    const int row = t >> 2, qd = t & 3;
    const float* src = &Cs[row * 132 + qd * 32];
    float* cdst = &C[(size_t)(rowbase + row) * ED + colbase + qd * 32];
    float4 vv[8];
    #pragma unroll
    for (int i = 0; i < 8; ++i) vv[i] = *(const float4*)(src + i * 4);
    #pragma unroll
    for (int i = 0; i < 8; ++i) *(float4*)(cdst + i * 4) = vv[i];
    uint4 pk[4];
    #pragma unroll
    for (int i = 0; i < 4; ++i)
      pk[i] = make_uint4(pkbf(vv[2*i].x, vv[2*i].y), pkbf(vv[2*i].z, vv[2*i].w),
                         pkbf(vv[2*i+1].x, vv[2*i+1].y), pkbf(vv[2*i+1].z, vv[2*i+1].w));
    uint4* pdst = (uint4*)&Pbf[(size_t)(rowbase + row) * ED + colbase + qd * 32];
    #pragma unroll
    for (int i = 0; i < 4; ++i) pdst[i] = pk[i];
  }
}

// ---------------- code-streaming MFMA distance (uniform-base staging) --------
// R16 structure; staging addresses = uniform chunk base (SGPR) + constant
// per-lane offset (VGPR) instead of rolling per-lane 64-bit pointers.
__global__ __launch_bounds__(512, 4) void mfma_dist(
    const ushort* __restrict__ CBbf, const ushort* __restrict__ Pbf,
    const float* __restrict__ cnAdj, uint4* __restrict__ top2s)
{
  __shared__ uint4 Tile[4096];                 // 64 KB: P-stage, then 2x32KB dbuf
  __shared__ __align__(16) float cnL[2][64];
  __shared__ ull msh[128][2][2];

  const int bx = blockIdx.x;
  const int h = bx & 3;                 // code quarter
  const int rowbase = (bx >> 2) * 128;
  const int cq0 = h * 2048;
  const int t = threadIdx.x, l = t & 63, w = t >> 6;
  const int rg = w >> 1, cg = w & 1;
  const int c0 = l & 15, g = l >> 4;

  // ---- P prologue: stage 128x256 bf16 (64 KB), swizzle (u + 4*row) & 31 ----
  {
    const ushort* gb = Pbf + ((size_t)rowbase << 8);
    #pragma unroll
    for (int i = 0; i < 8; ++i) {
      int lin = i * 8192 + t * 16;
      int crow = lin >> 9;
      int u = (lin >> 4) & 31;
      GLOAD_LDS16(gb + ((size_t)crow << 8) + (((u - 4 * crow) & 31) << 3),
                  (char*)Tile + lin);
    }
  }
  __syncthreads();
  bf16x8 breg[2][8];
  {
    const char* Tb = (const char*)Tile;
    #pragma unroll
    for (int rj = 0; rj < 2; ++rj) {
      const int row = rg * 32 + rj * 16 + c0;
      #pragma unroll
      for (int kk = 0; kk < 8; ++kk)
        breg[rj][kk] = *(const bf16x8*)(Tb + row * 512 + (((kk * 4 + g + 4 * row) & 31) << 4));
    }
  }
  __syncthreads();

  const int cl0 = cg * 32 + c0;        // A rows for ci=0 / ci=1
  const int cl1 = cg * 32 + 16 + c0;
  const int ab0 = cl0 * 512;
  const int ab1 = cl1 * 512;
  const int cc0 = cg * 32 + g * 4;     // cnL offsets for ci=0 / ci=1
  const int cc1 = cg * 32 + 16 + g * 4;

  ull k1[2] = {~0ull, ~0ull};
  ull k2[2] = {~0ull, ~0ull};

  // constant per-lane staging offsets; chunk base is uniform (SGPR adds)
  int loff[4], ldsoff[4];
  #pragma unroll
  for (int i = 0; i < 4; ++i) {
    int lin = i * 8192 + t * 16;
    int crow = lin >> 9;
    int u = (lin >> 4) & 31;
    loff[i]   = (crow << 9) + (((u - 4 * crow) & 31) << 4);
    ldsoff[i] = lin;
  }
  const char*  cbB = (const char*)CBbf + ((size_t)cq0 << 9);  // quarter base (bytes)
  const float* cnQ = cnAdj + cq0;

  #define STAGE(buf, c)                                                   \
    { char* db = (char*)Tile + (buf) * 32768;                             \
      const char* gsrc = cbB + (size_t)(c) * 32768;                       \
      _Pragma("unroll")                                                   \
      for (int i = 0; i < 4; ++i)                                         \
        GLOAD_LDS16(gsrc + loff[i], db + ldsoff[i]);                      \
      if (w == 0) GLOAD_LDS4(cnQ + (c) * 64 + l, (char*)&cnL[buf][0]); }

  STAGE(0, 0);
  __syncthreads();
  for (int ch = 0; ch < 32; ++ch) {
    const int buf = ch & 1;
    if (ch < 31) STAGE(buf ^ 1, ch + 1);
    // acc init = cnAdj (accumulator directly produces v' = cnAdj - 2*dot)
    f32x4 cn0 = *(const f32x4*)&cnL[buf][cc0];
    f32x4 cn1 = *(const f32x4*)&cnL[buf][cc1];
    f32x4 acc[2][2];
    acc[0][0] = cn0; acc[0][1] = cn0;
    acc[1][0] = cn1; acc[1][1] = cn1;
    {
      const char* Tb = (const char*)Tile + buf * 32768;
      int u0 = (g + 4 * cl0) & 31;
      int u1 = (g + 4 * cl1) & 31;
      #pragma unroll
      for (int kk = 0; kk < 8; ++kk) {
        bf16x8 a0 = *(const bf16x8*)(Tb + ab0 + (u0 << 4));
        bf16x8 a1 = *(const bf16x8*)(Tb + ab1 + (u1 << 4));
        u0 = (u0 + 4) & 31;
        u1 = (u1 + 4) & 31;
        #pragma unroll
        for (int rj = 0; rj < 2; ++rj) {
          acc[0][rj] = __builtin_amdgcn_mfma_f32_16x16x32_bf16(a0, breg[rj][kk], acc[0][rj], 0, 0, 0);
          acc[1][rj] = __builtin_amdgcn_mfma_f32_16x16x32_bf16(a1, breg[rj][kk], acc[1][rj], 0, 0, 0);
        }
      }
    }
    // branchless exact-key fold (u64 lexicographic top-2)
    #pragma unroll
    for (int ci = 0; ci < 2; ++ci) {
      const int cbase = cq0 + ch * 64 + cg * 32 + ci * 16 + g * 4;
      #pragma unroll
      for (int rj = 0; rj < 2; ++rj)
        #pragma unroll
        for (int q = 0; q < 4; ++q) {
          ull key = ((ull)f2u(acc[ci][rj][q]) << 32) | (ull)(cbase + q);
          ull mx = k1[rj] > key ? k1[rj] : key;
          k1[rj] = k1[rj] < key ? k1[rj] : key;
          k2[rj] = k2[rj] < mx ? k2[rj] : mx;
        }
    }
    // bucket flush every 8 chunks (512 codes)
    if ((ch & 7) == 7) {
      #pragma unroll
      for (int rj = 0; rj < 2; ++rj) {
        ull K1 = k1[rj], K2 = k2[rj];
        #pragma unroll
        for (int mask = 16; mask <= 32; mask <<= 1) {
          ull o1 = __shfl_xor(K1, mask);
          ull o2 = __shfl_xor(K2, mask);
          ull mx  = K1 > o1 ? K1 : o1;
          ull mn2 = K2 < o2 ? K2 : o2;
          K1 = K1 < o1 ? K1 : o1;
          K2 = mx < mn2 ? mx : mn2;
        }
        if (g == 0) {
          msh[rg * 32 + rj * 16 + c0][cg][0] = K1;
          msh[rg * 32 + rj * 16 + c0][cg][1] = K2;
        }
        k1[rj] = ~0ull; k2[rj] = ~0ull;
      }
      __syncthreads();
      if (t < 128) {
        ull a1 = msh[t][0][0], a2 = msh[t][0][1];
        ull b1 = msh[t][1][0], b2 = msh[t][1][1];
        ull K1  = a1 < b1 ? a1 : b1;
        ull mx  = a1 > b1 ? a1 : b1;
        ull mn2 = a2 < b2 ? a2 : b2;
        ull K2  = mx < mn2 ? mx : mn2;
        top2s[(size_t)(h * 4 + (ch >> 3)) * NR + rowbase + t] =
            make_uint4((uint32)(K1 >> 32), (uint32)K1, (uint32)(K2 >> 32), (uint32)K2);
      }
    }
    __syncthreads();
  }
  #undef STAGE
}

// ---------------- fused exact rescore + gather + vq_loss (top2s in ws) -------
__global__ __launch_bounds__(256) void rescore_gather(
    const uint4* __restrict__ top2s, const float* __restrict__ P,
    const float* __restrict__ CBF, const float* __restrict__ cnorm,
    float* __restrict__ outq, float* __restrict__ out_ids,
    float* __restrict__ loss)
{
  const int t = threadIdx.x, l = t & 63, w = t >> 6;
  const int row = blockIdx.x * 4 + w;
  float m1 = 3.4e38f, m2 = 3.4e38f;     // shifted-domain values (v' = d2 + VSHIFT)
  uint32 i1 = 0, i2 = 0;
  if (l < NBUCK) {
    uint4 e = top2s[(size_t)l * NR + row];
    m1 = u2f(e.x); i1 = e.y & 8191u;
    m2 = u2f(e.z); i2 = e.w & 8191u;
  }
  float rm = m1;
  #pragma unroll
  for (int mask = 1; mask < 64; mask <<= 1) rm = fminf(rm, __shfl_xor(rm, mask));
  const float thr = rm + DELTA;         // shift cancels in the comparison
  ull qm1 = __ballot(l < NBUCK && m1 <= thr);
  ull qm2 = __ballot(l < NBUCK && m2 <= thr);
  float4 p = *(const float4*)&P[(size_t)row * ED + l * 4];
  double bd = 1e300; int bi = 0x7fffffff;
  #pragma unroll
  for (int cand = 0; cand < 2; ++cand) {
    ull qm = cand ? qm2 : qm1;
    uint32 myi = cand ? i2 : i1;
    while (qm) {
      int b = __ffsll(qm) - 1; qm &= qm - 1;
      int idx = __shfl((int)myi, b);
      const float4 c = *(const float4*)&CBF[(size_t)idx * ED + l * 4];
      double s = (double)p.x * c.x + (double)p.y * c.y + (double)p.z * c.z + (double)p.w * c.w;
      #pragma unroll
      for (int mask = 1; mask < 64; mask <<= 1) s += __shfl_xor(s, mask);
      double d2 = (double)cnorm[idx] - 2.0 * s;
      if (d2 < bd || (d2 == bd && idx < bi)) { bd = d2; bi = idx; }
    }
  }
  // all lanes hold bi: gather CB[bi], write quantized, accumulate loss
  float4 q = *(const float4*)&CBF[(size_t)bi * ED + l * 4];
  *(float4*)&outq[(size_t)row * ED + l * 4] = q;
  float dx = p.x - q.x, dy = p.y - q.y, dz = p.z - q.z, dw = p.w - q.w;
  float sl = dx * dx + dy * dy + dz * dz + dw * dw;
  #pragma unroll
  for (int off = 32; off; off >>= 1) sl += __shfl_down(sl, off, 64);
  __shared__ float partial[4];
  if (l == 0) {
    partial[w] = sl;
    out_ids[row] = (float)bi;
  }
  __syncthreads();
  if (t == 0) {
    float tot = partial[0] + partial[1] + partial[2] + partial[3];
    atomicAdd(loss, tot * (1.25f / ((float)NR * (float)ED)));
  }
}

// ---------------- fallback: rescore (ids only) ----------------
__global__ __launch_bounds__(256) void rescore_kernel(
    const uint4* __restrict__ top2s, const float* __restrict__ P,
    const float* __restrict__ CBF, const float* __restrict__ cnorm,
    int* __restrict__ ids, float* __restrict__ out_ids)
{
  const int t = threadIdx.x, l = t & 63, w = t >> 6;
  const int row = blockIdx.x * 4 + w;
  float m1 = 3.4e38f, m2 = 3.4e38f;
  uint32 i1 = 0, i2 = 0;
  if (l < NBUCK) {
    uint4 e = top2s[(size_t)l * NR + row];
    m1 = u2f(e.x); i1 = e.y & 8191u;
    m2 = u2f(e.z); i2 = e.w & 8191u;
  }
  float rm = m1;
  #pragma unroll
  for (int mask = 1; mask < 64; mask <<= 1) rm = fminf(rm, __shfl_xor(rm, mask));
  const float thr = rm + DELTA;
  ull qm1 = __ballot(l < NBUCK && m1 <= thr);
  ull qm2 = __ballot(l < NBUCK && m2 <= thr);
  float4 p = *(const float4*)&P[(size_t)row * ED + l * 4];
  double bd = 1e300; int bi = 0x7fffffff;
  #pragma unroll
  for (int cand = 0; cand < 2; ++cand) {
    ull qm = cand ? qm2 : qm1;
    uint32 myi = cand ? i2 : i1;
    while (qm) {
      int b = __ffsll(qm) - 1; qm &= qm - 1;
      int idx = __shfl((int)myi, b);
      const float4 c = *(const float4*)&CBF[(size_t)idx * ED + l * 4];
      double s = (double)p.x * c.x + (double)p.y * c.y + (double)p.z * c.z + (double)p.w * c.w;
      #pragma unroll
      for (int mask = 1; mask < 64; mask <<= 1) s += __shfl_xor(s, mask);
      double d2 = (double)cnorm[idx] - 2.0 * s;
      if (d2 < bd || (d2 == bd && idx < bi)) { bd = d2; bi = idx; }
    }
  }
  if (l == 0) {
    ids[row] = bi;
    out_ids[row] = (float)bi;
  }
}

// ---------------- fallback: gather quantized + vq_loss ----------------
__global__ __launch_bounds__(256) void gather_loss(
    const float* __restrict__ P, const float* __restrict__ CB,
    const int* __restrict__ ids, float* __restrict__ outq,
    float* __restrict__ loss)
{
  const int t = threadIdx.x, lane = t & 63, w = t >> 6;
  const int row = blockIdx.x * 4 + w;
  const int id = ids[row];
  float4 q = *(const float4*)&CB[(size_t)id * ED + lane * 4];
  float4 p = *(const float4*)&P[(size_t)row * ED + lane * 4];
  *(float4*)&outq[(size_t)row * ED + lane * 4] = q;
  float dx = p.x - q.x, dy = p.y - q.y, dz = p.z - q.z, dw = p.w - q.w;
  float s = dx * dx + dy * dy + dz * dz + dw * dw;
  #pragma unroll
  for (int off = 32; off; off >>= 1) s += __shfl_down(s, off, 64);
  __shared__ float partial[4];
  if (lane == 0) partial[w] = s;
  __syncthreads();
  if (t == 0){
    float tot = partial[0] + partial[1] + partial[2] + partial[3];
    atomicAdd(loss, tot * (1.25f / ((float)NR * (float)ED)));
  }
}

extern "C" void kernel_launch(void* const* d_in, const int* in_sizes, int n_in,
                              void* d_out, int out_size, void* d_ws, size_t ws_size,
                              hipStream_t stream) {
    const float* values = (const float*)d_in[0];   // [8,2048,1024]
    const float* W      = (const float*)d_in[1];   // [256,1024]
    const float* bias   = (const float*)d_in[2];   // [256]
    const float* CB     = (const float*)d_in[3];   // [8192,256]

    float* out      = (float*)d_out;
    float* out_q    = out;                                  // NR*ED (16 MB)
    float* out_ids  = out + (size_t)NR * ED;                // NR
    float* out_loss = out_ids + NR;                         // 1

    // ws layout
    float*  proj  = (float*)d_ws;                           // 16 MB
    float*  cnorm = proj + (size_t)NR * ED;                 // 32 KB
    float*  cnAdj = cnorm + KC;                             // 32 KB
    ushort* CBbf  = (ushort*)(cnAdj + KC);                  // 4 MB
    int*    ids   = (int*)(CBbf + (size_t)KC * ED);         // 64 KB
    ushort* Whi   = (ushort*)(ids + NR);                    // 512 KB
    ushort* Wlo   = Whi + (size_t)ED * VD;                  // 512 KB
    uint4*  top2s_ws = (uint4*)(Wlo + (size_t)ED * VD);     // 4 MB
    size_t  need  = (size_t)((char*)(top2s_ws + (size_t)NBUCK * NR) - (char*)d_ws);
    const bool fuse = ws_size >= need;

    // If ws can't hold top2s, fall back to the out_q-scratch layout:
    //   [0, 4MB) of out_q: top2s ; [4MB,12MB): Pbf (always in out_q)
    uint4*  top2s = fuse ? top2s_ws : (uint4*)out_q;
    ushort* Pbf   = (ushort*)(out_q + (size_t)NBUCK * NR * 4);  // +4MB in floats

    prep_kernel<<<KC / 4, 256, 0, stream>>>(W, CB, cnorm, cnAdj, CBbf, Whi, Wlo, out_loss);
    proj_mfma<<<dim3(NR / 128, ED / 128), 512, 0, stream>>>(values, Whi, Wlo, bias, proj, Pbf);
    mfma_dist<<<512, 512, 0, stream>>>(CBbf, Pbf, cnAdj, top2s);
    if (fuse) {
      rescore_gather<<<NR / 4, 256, 0, stream>>>(top2s, proj, CB, cnorm,
                                                 out_q, out_ids, out_loss);
    } else {
      rescore_kernel<<<NR / 4, 256, 0, stream>>>(top2s, proj, CB, cnorm, ids, out_ids);
      gather_loss<<<NR / 4, 256, 0, stream>>>(proj, CB, ids, out_q, out_loss);
    }
}